// Round 2
// baseline (1101.009 us; speedup 1.0000x reference)
//
#include <hip/hip_runtime.h>
#include <math.h>

#define NN 100000
#define NE 3200000
#define NG 256
#define HD 16
#define FIN 7

// Bucketed counting sort parameters
#define RB 7                 // log2(bucket node range)
#define RSZ 128              // nodes per bucket
#define NBUK 782             // ceil(NN / RSZ) ; 782*128 = 100096
#define FB 512               // fill/hist blocks
#define CHUNK 6250           // NE / FB (exact)

static constexpr float SLOPE = 0.22916666666666666f;  // eval-mode RReLU mean slope

__device__ __forceinline__ float rrelu_f(float a) {
    return a >= 0.f ? a : SLOPE * a;
}

// ---------------------------------------------------------------------------
// K0: h1 = x @ W1
__global__ __launch_bounds__(256) void k_node_prep(
        const float* __restrict__ x, const float* __restrict__ W1,
        float* __restrict__ h1) {
    int t = blockIdx.x * 256 + threadIdx.x;
    if (t >= NN * HD) return;
    int i = t >> 4, f = t & 15;
    float acc = 0.f;
#pragma unroll
    for (int k = 0; k < FIN; ++k) acc += x[i * FIN + k] * W1[k * HD + f];
    h1[t] = acc;
}

// K1: per-block bucket histogram of col>>RB (LDS bins, no global atomics)
__global__ __launch_bounds__(256) void k_hist(
        const int* __restrict__ col, int* __restrict__ hist) {
    __shared__ int bins[NBUK];
    for (int i = threadIdx.x; i < NBUK; i += 256) bins[i] = 0;
    __syncthreads();
    int base = blockIdx.x * CHUNK;
    for (int i = threadIdx.x; i < CHUNK; i += 256)
        atomicAdd(&bins[col[base + i] >> RB], 1);
    __syncthreads();
    for (int i = threadIdx.x; i < NBUK; i += 256)
        hist[blockIdx.x * NBUK + i] = bins[i];
}

// K2a: per-bucket exclusive scan over the FB blocks -> pre[b][j], totals
__global__ __launch_bounds__(FB) void k_scan_a(
        const int* __restrict__ hist, int* __restrict__ pre, int* __restrict__ tot) {
    __shared__ int s[FB];
    int t = threadIdx.x;
    int v = hist[t * NBUK + blockIdx.x];
    s[t] = v;
    __syncthreads();
    for (int d = 1; d < FB; d <<= 1) {
        int add = (t >= d) ? s[t - d] : 0;
        __syncthreads();
        s[t] += add;
        __syncthreads();
    }
    pre[blockIdx.x * FB + t] = s[t] - v;       // exclusive prefix within bucket
    if (t == FB - 1) tot[blockIdx.x] = s[t];   // bucket total
}

// K2b: scan bucket totals -> bstart[0..NBUK]
__global__ __launch_bounds__(1024) void k_scan_b(
        const int* __restrict__ tot, int* __restrict__ bstart) {
    __shared__ int s[1024];
    int t = threadIdx.x;
    int v = (t < NBUK) ? tot[t] : 0;
    s[t] = v;
    __syncthreads();
    for (int d = 1; d < 1024; d <<= 1) {
        int add = (t >= d) ? s[t - d] : 0;
        __syncthreads();
        s[t] += add;
        __syncthreads();
    }
    if (t < NBUK) bstart[t + 1] = s[t];
    if (t == 0) bstart[0] = 0;
}

// K3: stable-ish fill: scatter edges into bucket-grouped order.
// payload: spack = (local_col << 17) | row  (row < 2^17, lc < 2^7), sw = weight
__global__ __launch_bounds__(256) void k_fill(
        const int* __restrict__ row, const int* __restrict__ col,
        const float* __restrict__ ew,
        const int* __restrict__ pre, const int* __restrict__ bstart,
        unsigned int* __restrict__ spack, float* __restrict__ sw) {
    __shared__ int lbase[NBUK];
    __shared__ int cnt[NBUK];
    for (int i = threadIdx.x; i < NBUK; i += 256) {
        lbase[i] = bstart[i] + pre[i * FB + blockIdx.x];
        cnt[i] = 0;
    }
    __syncthreads();
    int base = blockIdx.x * CHUNK;
    for (int i = threadIdx.x; i < CHUNK; i += 256) {
        int c = col[base + i];
        int b = c >> RB;
        int loc = atomicAdd(&cnt[b], 1);
        int pos = lbase[b] + loc;
        spack[pos] = ((unsigned)(c & (RSZ - 1)) << 17) | (unsigned)row[base + i];
        sw[pos] = ew[base + i];
    }
}

// K4: degrees per bucket via LDS accumulate -> dis1, dis2
__global__ __launch_bounds__(256) void k_deg(
        const unsigned int* __restrict__ spack, const float* __restrict__ sw,
        const int* __restrict__ bstart,
        float* __restrict__ dis1, float* __restrict__ dis2) {
    __shared__ float sdeg[RSZ];
    __shared__ int scnt[RSZ];
    int t = threadIdx.x;
    if (t < RSZ) { sdeg[t] = 0.f; scnt[t] = 0; }
    __syncthreads();
    int s0 = bstart[blockIdx.x], s1 = bstart[blockIdx.x + 1];
    for (int j = s0 + t; j < s1; j += 256) {
        unsigned p = spack[j];
        int lc = p >> 17;
        atomicAdd(&sdeg[lc], sw[j]);
        atomicAdd(&scnt[lc], 1);
    }
    __syncthreads();
    int node = blockIdx.x * RSZ + t;
    if (t < RSZ && node < NN) {
        dis1[node] = rsqrtf(sdeg[t] + 1.f);          // +1 self loop
        dis2[node] = rsqrtf((float)scnt[t] + 1.f);
    }
}

// K5: conv1 aggregation: acc[c] += h1[r] * dis1[r] * w ; epilogue * dis1[c] + self + bias
__global__ __launch_bounds__(256) void k_conv1(
        const unsigned int* __restrict__ spack, const float* __restrict__ sw,
        const int* __restrict__ bstart,
        const float* __restrict__ h1, const float* __restrict__ dis1,
        const float* __restrict__ b1, float* __restrict__ h1out) {
    __shared__ float acc[RSZ * HD];
    int t = threadIdx.x;
    for (int i = t; i < RSZ * HD; i += 256) acc[i] = 0.f;
    __syncthreads();
    int f = t & 15, slot = t >> 4;
    int s0 = bstart[blockIdx.x], s1 = bstart[blockIdx.x + 1];
    for (int j = s0 + slot; j < s1; j += 16) {
        unsigned p = spack[j];
        int r = p & 0x1FFFF;
        int lc = p >> 17;
        float coef = dis1[r] * sw[j];
        atomicAdd(&acc[lc * HD + f], h1[r * HD + f] * coef);
    }
    __syncthreads();
    for (int i = t; i < RSZ * HD; i += 256) {
        int ln = i >> 4, ff = i & 15;
        int node = blockIdx.x * RSZ + ln;
        if (node < NN) {
            float d = dis1[node];
            float hv = h1[node * HD + ff];
            h1out[node * HD + ff] = acc[i] * d + hv * d * d + b1[ff];
        }
    }
}

// K6: neighbor max pool: LDS int-max trick, epilogue max with self
__global__ __launch_bounds__(256) void k_pool(
        const unsigned int* __restrict__ spack, const int* __restrict__ bstart,
        const float* __restrict__ h1out, float* __restrict__ pool) {
    __shared__ int acc[RSZ * HD];
    int t = threadIdx.x;
    for (int i = t; i < RSZ * HD; i += 256) acc[i] = __float_as_int(-3.402823466e38f);
    __syncthreads();
    int f = t & 15, slot = t >> 4;
    int s0 = bstart[blockIdx.x], s1 = bstart[blockIdx.x + 1];
    for (int j = s0 + slot; j < s1; j += 16) {
        unsigned p = spack[j];
        int r = p & 0x1FFFF;
        int lc = p >> 17;
        float v = h1out[r * HD + f];
        int* a = &acc[lc * HD + f];
        if (v >= 0.f) atomicMax(a, __float_as_int(v));
        else          atomicMin((unsigned int*)a, __float_as_uint(v));
    }
    __syncthreads();
    for (int i = t; i < RSZ * HD; i += 256) {
        int ln = i >> 4, ff = i & 15;
        int node = blockIdx.x * RSZ + ln;
        if (node < NN)
            pool[node * HD + ff] = fmaxf(__int_as_float(acc[i]), h1out[node * HD + ff]);
    }
}

// K7: h2s = (pool @ W2) * dis2[i]   (pre-scaled by source-side norm)
__global__ __launch_bounds__(256) void k_h2(
        const float* __restrict__ pool, const float* __restrict__ W2,
        const float* __restrict__ dis2, float* __restrict__ h2s) {
    int t = blockIdx.x * 256 + threadIdx.x;
    if (t >= NN * HD) return;
    int i = t >> 4, f = t & 15;
    float a = 0.f;
#pragma unroll
    for (int k = 0; k < HD; ++k) a += pool[i * HD + k] * W2[k * HD + f];
    h2s[t] = a * dis2[i];
}

// K8: conv2 aggregation + fused residual-relu epilogue -> hfin
__global__ __launch_bounds__(256) void k_conv2(
        const unsigned int* __restrict__ spack, const int* __restrict__ bstart,
        const float* __restrict__ h2s, const float* __restrict__ dis2,
        const float* __restrict__ pool, const float* __restrict__ b2,
        float* __restrict__ hfin) {
    __shared__ float acc[RSZ * HD];
    int t = threadIdx.x;
    for (int i = t; i < RSZ * HD; i += 256) acc[i] = 0.f;
    __syncthreads();
    int f = t & 15, slot = t >> 4;
    int s0 = bstart[blockIdx.x], s1 = bstart[blockIdx.x + 1];
    for (int j = s0 + slot; j < s1; j += 16) {
        unsigned p = spack[j];
        int r = p & 0x1FFFF;
        int lc = p >> 17;
        atomicAdd(&acc[lc * HD + f], h2s[r * HD + f]);
    }
    __syncthreads();
    for (int i = t; i < RSZ * HD; i += 256) {
        int ln = i >> 4, ff = i & 15;
        int node = blockIdx.x * RSZ + ln;
        if (node < NN) {
            int idx = node * HD + ff;
            float d = dis2[node];
            float val = pool[idx] + (acc[i] + h2s[idx]) * d + b2[ff];
            hfin[idx] = fmaxf(val, 0.f);
        }
    }
}

// K9: global max pool per graph; batch = (i*G)//N -> contiguous ranges
__global__ __launch_bounds__(256) void k_graph_max(
        const float* __restrict__ hfin, float* __restrict__ gbuf) {
    int g = blockIdx.x;
    int start = (g * NN + NG - 1) / NG;
    int end   = ((g + 1) * NN + NG - 1) / NG;
    int f = threadIdx.x & 15, sub = threadIdx.x >> 4;
    float m = -3.402823466e38f;
    for (int i = start + sub; i < end; i += 16)
        m = fmaxf(m, hfin[i * HD + f]);
    __shared__ float lds[256];
    lds[threadIdx.x] = m;
    __syncthreads();
    if (threadIdx.x < 16) {
        float mm = lds[threadIdx.x];
#pragma unroll
        for (int s = 1; s < 16; ++s) mm = fmaxf(mm, lds[s * 16 + threadIdx.x]);
        gbuf[g * HD + threadIdx.x] = mm;
    }
}

// K10: head MLP on [G,16]; one thread per graph row
__global__ __launch_bounds__(256) void k_mlp(
        const float* __restrict__ gbuf,
        const float* __restrict__ Wl1, const float* __restrict__ bl1,
        const float* __restrict__ Wl3, const float* __restrict__ bl3,
        const float* __restrict__ Wl4, const float* __restrict__ bl4,
        float* __restrict__ out) {
    __shared__ float sW1[256], sW3[256], sW4[16], sb1[16], sb3[16];
    __shared__ float sb4;
    int tid = threadIdx.x;
    sW1[tid] = Wl1[tid];
    sW3[tid] = Wl3[tid];
    if (tid < 16) { sW4[tid] = Wl4[tid]; sb1[tid] = bl1[tid]; sb3[tid] = bl3[tid]; }
    if (tid == 0) sb4 = bl4[0];
    __syncthreads();

    float v[16], t1[16], t2[16];
#pragma unroll
    for (int f = 0; f < 16; ++f) v[f] = gbuf[tid * 16 + f];
#pragma unroll
    for (int f = 0; f < 16; ++f) {
        float a = sb1[f] + v[f];
#pragma unroll
        for (int k = 0; k < 16; ++k) a += v[k] * sW1[k * 16 + f];
        t1[f] = rrelu_f(a);
    }
#pragma unroll
    for (int f = 0; f < 16; ++f) {
        float a = sb3[f] + t1[f];
#pragma unroll
        for (int k = 0; k < 16; ++k) a += t1[k] * sW3[k * 16 + f];
        t2[f] = rrelu_f(a);
    }
    float o = sb4;
#pragma unroll
    for (int k = 0; k < 16; ++k) o += t2[k] * sW4[k];
    out[tid] = rrelu_f(o);
}

extern "C" void kernel_launch(void* const* d_in, const int* in_sizes, int n_in,
                              void* d_out, int out_size, void* d_ws, size_t ws_size,
                              hipStream_t stream) {
    const float* x   = (const float*)d_in[0];
    const int*   ei  = (const int*)  d_in[1];   // [2, E] flat
    const float* ew  = (const float*)d_in[3];
    const float* W1  = (const float*)d_in[4];
    const float* b1  = (const float*)d_in[5];
    const float* W2  = (const float*)d_in[6];
    const float* b2  = (const float*)d_in[7];
    const float* Wl1 = (const float*)d_in[8];
    const float* bl1 = (const float*)d_in[9];
    const float* Wl3 = (const float*)d_in[10];
    const float* bl3 = (const float*)d_in[11];
    const float* Wl4 = (const float*)d_in[12];
    const float* bl4 = (const float*)d_in[13];
    const int* row = ei;
    const int* col = ei + NE;

    // workspace layout (element offsets)
    float* ws = (float*)d_ws;
    float* h1    = ws;                      // NN*HD
    float* h1out = h1    + NN * HD;         // NN*HD
    float* pool  = h1out + NN * HD;         // NN*HD
    float* h2s   = pool  + NN * HD;         // NN*HD
    float* hfin  = h1;                      // reuse h1 (dead after k_conv1)
    float* dis1  = h2s   + NN * HD;         // NN
    float* dis2  = dis1  + NN;              // NN
    float* gbuf  = dis2  + NN;              // NG*HD
    float* swt   = gbuf  + NG * HD;         // NE
    unsigned int* spack = (unsigned int*)(swt + NE);    // NE
    int* hist   = (int*)(spack + NE);       // FB*NBUK
    int* pre    = hist + FB * NBUK;         // NBUK*FB
    int* tot    = pre + NBUK * FB;          // NBUK
    int* bstart = tot + NBUK;               // NBUK+1

    const int B = 256;
    const int gridNodeF = (NN * HD + B - 1) / B;

    k_node_prep<<<gridNodeF, B, 0, stream>>>(x, W1, h1);
    k_hist     <<<FB, B, 0, stream>>>(col, hist);
    k_scan_a   <<<NBUK, FB, 0, stream>>>(hist, pre, tot);
    k_scan_b   <<<1, 1024, 0, stream>>>(tot, bstart);
    k_fill     <<<FB, B, 0, stream>>>(row, col, ew, pre, bstart, spack, swt);
    k_deg      <<<NBUK, B, 0, stream>>>(spack, swt, bstart, dis1, dis2);
    k_conv1    <<<NBUK, B, 0, stream>>>(spack, swt, bstart, h1, dis1, b1, h1out);
    k_pool     <<<NBUK, B, 0, stream>>>(spack, bstart, h1out, pool);
    k_h2       <<<gridNodeF, B, 0, stream>>>(pool, W2, dis2, h2s);
    k_conv2    <<<NBUK, B, 0, stream>>>(spack, bstart, h2s, dis2, pool, b2, hfin);
    k_graph_max<<<NG, B, 0, stream>>>(hfin, gbuf);
    k_mlp      <<<1, B, 0, stream>>>(gbuf, Wl1, bl1, Wl3, bl3, Wl4, bl4, (float*)d_out);
}

// Round 3
// 924.057 us; speedup vs baseline: 1.1915x; 1.1915x over previous
//
#include <hip/hip_runtime.h>
#include <hip/hip_fp16.h>
#include <math.h>

#define NN 100000
#define NE 3200000
#define NG 256
#define HD 16
#define FIN 7

// Bucketed counting sort parameters
#define RB 7                 // log2(nodes per bucket)
#define RSZ 128              // nodes per bucket
#define NBUK 782             // ceil(NN / RSZ)
#define FB 512               // fill/hist blocks
#define CHUNK 6250           // NE / FB (exact)
#define ASTRIDE 17           // padded LDS accumulator row stride (breaks bank correlation)

static constexpr float SLOPE = 0.22916666666666666f;  // eval-mode RReLU mean slope

__device__ __forceinline__ float rrelu_f(float a) {
    return a >= 0.f ? a : SLOPE * a;
}

// monotonic float<->uint encoding for atomicMax-based float max
__device__ __forceinline__ unsigned encf(float v) {
    unsigned u = __float_as_uint(v);
    return u ^ (((unsigned)((int)u >> 31)) | 0x80000000u);
}
__device__ __forceinline__ float decf(unsigned u) {
    unsigned m = ((int)u < 0) ? 0x80000000u : 0xFFFFFFFFu;
    return __uint_as_float(u ^ m);
}
#define ENC_NEGINF 0x00800000u   // encf(-3.402823466e38f)

// ---------------------------------------------------------------------------
// K0: h1 = x @ W1 (fp32)
__global__ __launch_bounds__(256) void k_node_prep(
        const float* __restrict__ x, const float* __restrict__ W1,
        float* __restrict__ h1) {
    int t = blockIdx.x * 256 + threadIdx.x;
    if (t >= NN * HD) return;
    int i = t >> 4, f = t & 15;
    float acc = 0.f;
#pragma unroll
    for (int k = 0; k < FIN; ++k) acc += x[i * FIN + k] * W1[k * HD + f];
    h1[t] = acc;
}

// K1: per-block bucket histogram of col>>RB
__global__ __launch_bounds__(256) void k_hist(
        const int* __restrict__ col, int* __restrict__ hist) {
    __shared__ int bins[NBUK];
    for (int i = threadIdx.x; i < NBUK; i += 256) bins[i] = 0;
    __syncthreads();
    int base = blockIdx.x * CHUNK;
    for (int i = threadIdx.x; i < CHUNK; i += 256)
        atomicAdd(&bins[col[base + i] >> RB], 1);
    __syncthreads();
    for (int i = threadIdx.x; i < NBUK; i += 256)
        hist[blockIdx.x * NBUK + i] = bins[i];
}

// K2a: per-bucket exclusive scan over the FB blocks
__global__ __launch_bounds__(FB) void k_scan_a(
        const int* __restrict__ hist, int* __restrict__ pre, int* __restrict__ tot) {
    __shared__ int s[FB];
    int t = threadIdx.x;
    int v = hist[t * NBUK + blockIdx.x];
    s[t] = v;
    __syncthreads();
    for (int d = 1; d < FB; d <<= 1) {
        int add = (t >= d) ? s[t - d] : 0;
        __syncthreads();
        s[t] += add;
        __syncthreads();
    }
    pre[blockIdx.x * FB + t] = s[t] - v;
    if (t == FB - 1) tot[blockIdx.x] = s[t];
}

// K2b: scan bucket totals -> bstart[0..NBUK]
__global__ __launch_bounds__(1024) void k_scan_b(
        const int* __restrict__ tot, int* __restrict__ bstart) {
    __shared__ int s[1024];
    int t = threadIdx.x;
    int v = (t < NBUK) ? tot[t] : 0;
    s[t] = v;
    __syncthreads();
    for (int d = 1; d < 1024; d <<= 1) {
        int add = (t >= d) ? s[t - d] : 0;
        __syncthreads();
        s[t] += add;
        __syncthreads();
    }
    if (t < NBUK) bstart[t + 1] = s[t];
    if (t == 0) bstart[0] = 0;
}

// K3: fill bucket-grouped edge array; one uint2 {(lc<<17)|row, w_bits} per edge
__global__ __launch_bounds__(256) void k_fill(
        const int* __restrict__ row, const int* __restrict__ col,
        const float* __restrict__ ew,
        const int* __restrict__ pre, const int* __restrict__ bstart,
        uint2* __restrict__ spw) {
    __shared__ int lbase[NBUK];
    __shared__ int cnt[NBUK];
    for (int i = threadIdx.x; i < NBUK; i += 256) {
        lbase[i] = bstart[i] + pre[i * FB + blockIdx.x];
        cnt[i] = 0;
    }
    __syncthreads();
    int base = blockIdx.x * CHUNK;
    for (int i = threadIdx.x; i < CHUNK; i += 256) {
        int c = col[base + i];
        int b = c >> RB;
        int loc = atomicAdd(&cnt[b], 1);
        int pos = lbase[b] + loc;
        spw[pos] = make_uint2(((unsigned)(c & (RSZ - 1)) << 17) | (unsigned)row[base + i],
                              __float_as_uint(ew[base + i]));
    }
}

// K4: degrees -> dis1/dis2; fused: h1h = half2(h1 * dis1) (pre-scaled gather copy)
__global__ __launch_bounds__(256) void k_deg(
        const uint2* __restrict__ spw, const int* __restrict__ bstart,
        const float* __restrict__ h1,
        float* __restrict__ dis1, float* __restrict__ dis2,
        unsigned* __restrict__ h1h) {
    __shared__ float sdeg[RSZ];
    __shared__ int scnt[RSZ];
    __shared__ float sdis[RSZ];
    int t = threadIdx.x;
    if (t < RSZ) { sdeg[t] = 0.f; scnt[t] = 0; }
    __syncthreads();
    int s0 = bstart[blockIdx.x], s1 = bstart[blockIdx.x + 1];
    for (int j = s0 + t; j < s1; j += 256) {
        uint2 e = spw[j];
        int lc = e.x >> 17;
        atomicAdd(&sdeg[lc], __uint_as_float(e.y));
        atomicAdd(&scnt[lc], 1);
    }
    __syncthreads();
    int node0 = blockIdx.x * RSZ;
    if (t < RSZ && node0 + t < NN) {
        float d1 = rsqrtf(sdeg[t] + 1.f);
        dis1[node0 + t] = d1;
        sdis[t] = d1;
        dis2[node0 + t] = rsqrtf((float)scnt[t] + 1.f);
    }
    __syncthreads();
    for (int i = t; i < RSZ * 8; i += 256) {
        int ln = i >> 3, p = i & 7;
        int node = node0 + ln;
        if (node < NN) {
            float d = sdis[ln];
            __half2 hh = __floats2half2_rn(h1[node * HD + 2 * p] * d,
                                           h1[node * HD + 2 * p + 1] * d);
            h1h[node * 8 + p] = *(unsigned*)&hh;
        }
    }
}

// K5: conv1 aggregate: acc[c] += h1h[r] * w ; epilogue: *dis1[c] + self + bias
__global__ __launch_bounds__(1024) void k_conv1(
        const uint2* __restrict__ spw, const int* __restrict__ bstart,
        const unsigned* __restrict__ h1h, const float* __restrict__ h1,
        const float* __restrict__ dis1, const float* __restrict__ b1,
        float* __restrict__ h1out, unsigned* __restrict__ h1outh) {
    __shared__ float acc[RSZ * ASTRIDE];
    int t = threadIdx.x;
    for (int i = t; i < RSZ * ASTRIDE; i += 1024) acc[i] = 0.f;
    __syncthreads();
    int p = t & 7, slot = t >> 3;   // 128 slots x 8 feature-pairs
    int s0 = bstart[blockIdx.x], s1 = bstart[blockIdx.x + 1];
    for (int j = s0 + slot; j < s1; j += 128) {
        uint2 e = spw[j];
        int r = e.x & 0x1FFFF;
        int lc = e.x >> 17;
        float w = __uint_as_float(e.y);
        unsigned hv = h1h[r * 8 + p];
        float2 f2 = __half22float2(*(__half2*)&hv);
        atomicAdd(&acc[lc * ASTRIDE + 2 * p],     f2.x * w);
        atomicAdd(&acc[lc * ASTRIDE + 2 * p + 1], f2.y * w);
    }
    __syncthreads();
    int node0 = blockIdx.x * RSZ;
    for (int i = t; i < RSZ * HD; i += 1024) {
        int ln = i >> 4, ff = i & 15;
        int node = node0 + ln;
        if (node < NN) {
            float d = dis1[node];
            float hv = h1[node * HD + ff];
            float val = acc[ln * ASTRIDE + ff] * d + hv * d * d + b1[ff];
            h1out[node * HD + ff] = val;
            acc[ln * ASTRIDE + ff] = val;
        }
    }
    __syncthreads();
    for (int i = t; i < RSZ * 8; i += 1024) {
        int ln = i >> 3, pp = i & 7;
        int node = node0 + ln;
        if (node < NN) {
            __half2 hh = __floats2half2_rn(acc[ln * ASTRIDE + 2 * pp],
                                           acc[ln * ASTRIDE + 2 * pp + 1]);
            h1outh[node * 8 + pp] = *(unsigned*)&hh;
        }
    }
}

// K6: neighbor max pool via monotonic-uint atomicMax in LDS
__global__ __launch_bounds__(1024) void k_pool(
        const uint2* __restrict__ spw, const int* __restrict__ bstart,
        const unsigned* __restrict__ h1outh, const float* __restrict__ h1out,
        float* __restrict__ pool) {
    __shared__ unsigned acc[RSZ * ASTRIDE];
    int t = threadIdx.x;
    for (int i = t; i < RSZ * ASTRIDE; i += 1024) acc[i] = ENC_NEGINF;
    __syncthreads();
    int p = t & 7, slot = t >> 3;
    int s0 = bstart[blockIdx.x], s1 = bstart[blockIdx.x + 1];
    for (int j = s0 + slot; j < s1; j += 128) {
        unsigned ex = spw[j].x;
        int r = ex & 0x1FFFF;
        int lc = ex >> 17;
        unsigned hv = h1outh[r * 8 + p];
        float2 f2 = __half22float2(*(__half2*)&hv);
        atomicMax(&acc[lc * ASTRIDE + 2 * p],     encf(f2.x));
        atomicMax(&acc[lc * ASTRIDE + 2 * p + 1], encf(f2.y));
    }
    __syncthreads();
    int node0 = blockIdx.x * RSZ;
    for (int i = t; i < RSZ * HD; i += 1024) {
        int ln = i >> 4, ff = i & 15;
        int node = node0 + ln;
        if (node < NN)
            pool[node * HD + ff] = fmaxf(decf(acc[ln * ASTRIDE + ff]),
                                         h1out[node * HD + ff]);
    }
}

// K7: h2s = (pool @ W2) * dis2 (fp32 + fp16 copies); thread = (node, feature-pair)
__global__ __launch_bounds__(256) void k_h2(
        const float* __restrict__ pool, const float* __restrict__ W2,
        const float* __restrict__ dis2,
        float2* __restrict__ h2s, unsigned* __restrict__ h2sh) {
    int t = blockIdx.x * 256 + threadIdx.x;
    if (t >= NN * 8) return;
    int node = t >> 3, p = t & 7;
    float a0 = 0.f, a1 = 0.f;
#pragma unroll
    for (int k = 0; k < HD; ++k) {
        float pv = pool[node * HD + k];
        a0 += pv * W2[k * HD + 2 * p];
        a1 += pv * W2[k * HD + 2 * p + 1];
    }
    float d = dis2[node];
    a0 *= d; a1 *= d;
    h2s[t] = make_float2(a0, a1);
    __half2 hh = __floats2half2_rn(a0, a1);
    h2sh[t] = *(unsigned*)&hh;
}

// K8: conv2 aggregate + fused residual-relu epilogue -> hfin
__global__ __launch_bounds__(1024) void k_conv2(
        const uint2* __restrict__ spw, const int* __restrict__ bstart,
        const unsigned* __restrict__ h2sh, const float* __restrict__ h2s,
        const float* __restrict__ dis2, const float* __restrict__ pool,
        const float* __restrict__ b2, float* __restrict__ hfin) {
    __shared__ float acc[RSZ * ASTRIDE];
    int t = threadIdx.x;
    for (int i = t; i < RSZ * ASTRIDE; i += 1024) acc[i] = 0.f;
    __syncthreads();
    int p = t & 7, slot = t >> 3;
    int s0 = bstart[blockIdx.x], s1 = bstart[blockIdx.x + 1];
    for (int j = s0 + slot; j < s1; j += 128) {
        unsigned ex = spw[j].x;
        int r = ex & 0x1FFFF;
        int lc = ex >> 17;
        unsigned hv = h2sh[r * 8 + p];
        float2 f2 = __half22float2(*(__half2*)&hv);
        atomicAdd(&acc[lc * ASTRIDE + 2 * p],     f2.x);
        atomicAdd(&acc[lc * ASTRIDE + 2 * p + 1], f2.y);
    }
    __syncthreads();
    int node0 = blockIdx.x * RSZ;
    for (int i = t; i < RSZ * HD; i += 1024) {
        int ln = i >> 4, ff = i & 15;
        int node = node0 + ln;
        if (node < NN) {
            int idx = node * HD + ff;
            float d = dis2[node];
            float val = pool[idx] + (acc[ln * ASTRIDE + ff] + h2s[idx]) * d + b2[ff];
            hfin[idx] = fmaxf(val, 0.f);
        }
    }
}

// K9: global max pool per graph (batch = (i*G)//N -> contiguous ranges)
__global__ __launch_bounds__(256) void k_graph_max(
        const float* __restrict__ hfin, float* __restrict__ gbuf) {
    int g = blockIdx.x;
    int start = (g * NN + NG - 1) / NG;
    int end   = ((g + 1) * NN + NG - 1) / NG;
    int f = threadIdx.x & 15, sub = threadIdx.x >> 4;
    float m = -3.402823466e38f;
    for (int i = start + sub; i < end; i += 16)
        m = fmaxf(m, hfin[i * HD + f]);
    __shared__ float lds[256];
    lds[threadIdx.x] = m;
    __syncthreads();
    if (threadIdx.x < 16) {
        float mm = lds[threadIdx.x];
#pragma unroll
        for (int s = 1; s < 16; ++s) mm = fmaxf(mm, lds[s * 16 + threadIdx.x]);
        gbuf[g * HD + threadIdx.x] = mm;
    }
}

// K10: head MLP on [G,16]; one thread per graph row
__global__ __launch_bounds__(256) void k_mlp(
        const float* __restrict__ gbuf,
        const float* __restrict__ Wl1, const float* __restrict__ bl1,
        const float* __restrict__ Wl3, const float* __restrict__ bl3,
        const float* __restrict__ Wl4, const float* __restrict__ bl4,
        float* __restrict__ out) {
    __shared__ float sW1[256], sW3[256], sW4[16], sb1[16], sb3[16];
    __shared__ float sb4;
    int tid = threadIdx.x;
    sW1[tid] = Wl1[tid];
    sW3[tid] = Wl3[tid];
    if (tid < 16) { sW4[tid] = Wl4[tid]; sb1[tid] = bl1[tid]; sb3[tid] = bl3[tid]; }
    if (tid == 0) sb4 = bl4[0];
    __syncthreads();

    float v[16], t1[16], t2[16];
#pragma unroll
    for (int f = 0; f < 16; ++f) v[f] = gbuf[tid * 16 + f];
#pragma unroll
    for (int f = 0; f < 16; ++f) {
        float a = sb1[f] + v[f];
#pragma unroll
        for (int k = 0; k < 16; ++k) a += v[k] * sW1[k * 16 + f];
        t1[f] = rrelu_f(a);
    }
#pragma unroll
    for (int f = 0; f < 16; ++f) {
        float a = sb3[f] + t1[f];
#pragma unroll
        for (int k = 0; k < 16; ++k) a += t1[k] * sW3[k * 16 + f];
        t2[f] = rrelu_f(a);
    }
    float o = sb4;
#pragma unroll
    for (int k = 0; k < 16; ++k) o += t2[k] * sW4[k];
    out[tid] = rrelu_f(o);
}

extern "C" void kernel_launch(void* const* d_in, const int* in_sizes, int n_in,
                              void* d_out, int out_size, void* d_ws, size_t ws_size,
                              hipStream_t stream) {
    const float* x   = (const float*)d_in[0];
    const int*   ei  = (const int*)  d_in[1];   // [2, E] flat
    const float* ew  = (const float*)d_in[3];
    const float* W1  = (const float*)d_in[4];
    const float* b1  = (const float*)d_in[5];
    const float* W2  = (const float*)d_in[6];
    const float* b2  = (const float*)d_in[7];
    const float* Wl1 = (const float*)d_in[8];
    const float* bl1 = (const float*)d_in[9];
    const float* Wl3 = (const float*)d_in[10];
    const float* bl3 = (const float*)d_in[11];
    const float* Wl4 = (const float*)d_in[12];
    const float* bl4 = (const float*)d_in[13];
    const int* row = ei;
    const int* col = ei + NE;

    // workspace layout (floats)
    float* ws = (float*)d_ws;
    float* h1    = ws;                     // NN*HD ; reused as hfin after conv1
    float* h1out = h1    + NN * HD;        // NN*HD
    float* pool  = h1out + NN * HD;        // NN*HD ; hist aliases here pre-k_pool
    float* h2s   = pool  + NN * HD;        // NN*HD ; pre aliases here pre-k_h2
    float* dis1  = h2s   + NN * HD;        // NN
    float* dis2  = dis1  + NN;             // NN
    float* gbuf  = dis2  + NN;             // NG*HD
    unsigned* h1h    = (unsigned*)(gbuf + NG * HD);  // NN*8
    unsigned* h1outh = h1h    + NN * 8;              // NN*8
    unsigned* h2sh   = h1outh + NN * 8;              // NN*8
    uint2*    spw    = (uint2*)(h2sh + NN * 8);      // NE uint2
    int* tot    = (int*)(spw + NE);        // NBUK
    int* bstart = tot + NBUK;              // NBUK+1
    int* hist   = (int*)pool;              // FB*NBUK (dead before k_pool writes)
    int* pre    = (int*)h2s;               // NBUK*FB (dead before k_h2 writes)
    float* hfin = h1;

    const int B = 256;

    k_node_prep<<<(NN * HD + B - 1) / B, B, 0, stream>>>(x, W1, h1);
    k_hist     <<<FB, B, 0, stream>>>(col, hist);
    k_scan_a   <<<NBUK, FB, 0, stream>>>(hist, pre, tot);
    k_scan_b   <<<1, 1024, 0, stream>>>(tot, bstart);
    k_fill     <<<FB, B, 0, stream>>>(row, col, ew, pre, bstart, spw);
    k_deg      <<<NBUK, B, 0, stream>>>(spw, bstart, h1, dis1, dis2, h1h);
    k_conv1    <<<NBUK, 1024, 0, stream>>>(spw, bstart, h1h, h1, dis1, b1, h1out, h1outh);
    k_pool     <<<NBUK, 1024, 0, stream>>>(spw, bstart, h1outh, h1out, pool);
    k_h2       <<<(NN * 8 + B - 1) / B, B, 0, stream>>>(pool, W2, dis2, (float2*)h2s, h2sh);
    k_conv2    <<<NBUK, 1024, 0, stream>>>(spw, bstart, h2sh, h2s, dis2, pool, b2, hfin);
    k_graph_max<<<NG, B, 0, stream>>>(hfin, gbuf);
    k_mlp      <<<1, B, 0, stream>>>(gbuf, Wl1, bl1, Wl3, bl3, Wl4, bl4, (float*)d_out);
}

// Round 4
// 303.466 us; speedup vs baseline: 3.6281x; 3.0450x over previous
//
#include <hip/hip_runtime.h>
#include <hip/hip_fp16.h>
#include <math.h>

#define NN 100000
#define NE 3200000
#define NG 256
#define HD 16
#define FIN 7

// Bucketed counting sort parameters
#define RB 7                 // log2(nodes per bucket)
#define RSZ 128              // nodes per bucket
#define NBUK 782             // ceil(NN / RSZ)
#define FB 512               // fill/hist blocks
#define CHUNK 6250           // NE / FB (exact)
#define ASTRIDE 17           // padded LDS accumulator row stride

// fixed-point scales for native integer LDS atomics (fp32 LDS atomicAdd is a
// CAS slow path on gfx950 without unsafe-fp-atomics; ds_add_u32 is native)
#define S_CONV 524288.0f     // 2^19
#define INV_S_CONV 1.9073486328125e-6f
#define S_DEG 16777216.0f    // 2^24
#define INV_S_DEG 5.9604644775390625e-8f

static constexpr float SLOPE = 0.22916666666666666f;  // eval-mode RReLU mean slope

__device__ __forceinline__ float rrelu_f(float a) {
    return a >= 0.f ? a : SLOPE * a;
}

// monotonic float<->uint encoding for atomicMax-based float max
__device__ __forceinline__ unsigned encf(float v) {
    unsigned u = __float_as_uint(v);
    return u ^ (((unsigned)((int)u >> 31)) | 0x80000000u);
}
__device__ __forceinline__ float decf(unsigned u) {
    unsigned m = ((int)u < 0) ? 0x80000000u : 0xFFFFFFFFu;
    return __uint_as_float(u ^ m);
}
#define ENC_NEGINF 0x00800000u

// ---------------------------------------------------------------------------
// K0: h1 = x @ W1 (fp32)
__global__ __launch_bounds__(256) void k_node_prep(
        const float* __restrict__ x, const float* __restrict__ W1,
        float* __restrict__ h1) {
    int t = blockIdx.x * 256 + threadIdx.x;
    if (t >= NN * HD) return;
    int i = t >> 4, f = t & 15;
    float acc = 0.f;
#pragma unroll
    for (int k = 0; k < FIN; ++k) acc += x[i * FIN + k] * W1[k * HD + f];
    h1[t] = acc;
}

// K1: per-block bucket histogram of col>>RB
__global__ __launch_bounds__(256) void k_hist(
        const int* __restrict__ col, int* __restrict__ hist) {
    __shared__ int bins[NBUK];
    for (int i = threadIdx.x; i < NBUK; i += 256) bins[i] = 0;
    __syncthreads();
    int base = blockIdx.x * CHUNK;
    for (int i = threadIdx.x; i < CHUNK; i += 256)
        atomicAdd(&bins[col[base + i] >> RB], 1);
    __syncthreads();
    for (int i = threadIdx.x; i < NBUK; i += 256)
        hist[blockIdx.x * NBUK + i] = bins[i];
}

// K2a: per-bucket exclusive scan over the FB blocks
__global__ __launch_bounds__(FB) void k_scan_a(
        const int* __restrict__ hist, int* __restrict__ pre, int* __restrict__ tot) {
    __shared__ int s[FB];
    int t = threadIdx.x;
    int v = hist[t * NBUK + blockIdx.x];
    s[t] = v;
    __syncthreads();
    for (int d = 1; d < FB; d <<= 1) {
        int add = (t >= d) ? s[t - d] : 0;
        __syncthreads();
        s[t] += add;
        __syncthreads();
    }
    pre[blockIdx.x * FB + t] = s[t] - v;
    if (t == FB - 1) tot[blockIdx.x] = s[t];
}

// K2b: scan bucket totals -> bstart[0..NBUK]
__global__ __launch_bounds__(1024) void k_scan_b(
        const int* __restrict__ tot, int* __restrict__ bstart) {
    __shared__ int s[1024];
    int t = threadIdx.x;
    int v = (t < NBUK) ? tot[t] : 0;
    s[t] = v;
    __syncthreads();
    for (int d = 1; d < 1024; d <<= 1) {
        int add = (t >= d) ? s[t - d] : 0;
        __syncthreads();
        s[t] += add;
        __syncthreads();
    }
    if (t < NBUK) bstart[t + 1] = s[t];
    if (t == 0) bstart[0] = 0;
}

// K3: fill bucket-grouped edge array; one uint2 {(lc<<17)|row, w_bits} per edge
__global__ __launch_bounds__(256) void k_fill(
        const int* __restrict__ row, const int* __restrict__ col,
        const float* __restrict__ ew,
        const int* __restrict__ pre, const int* __restrict__ bstart,
        uint2* __restrict__ spw) {
    __shared__ int lbase[NBUK];
    __shared__ int cnt[NBUK];
    for (int i = threadIdx.x; i < NBUK; i += 256) {
        lbase[i] = bstart[i] + pre[i * FB + blockIdx.x];
        cnt[i] = 0;
    }
    __syncthreads();
    int base = blockIdx.x * CHUNK;
    for (int i = threadIdx.x; i < CHUNK; i += 256) {
        int c = col[base + i];
        int b = c >> RB;
        int loc = atomicAdd(&cnt[b], 1);
        int pos = lbase[b] + loc;
        spw[pos] = make_uint2(((unsigned)(c & (RSZ - 1)) << 17) | (unsigned)row[base + i],
                              __float_as_uint(ew[base + i]));
    }
}

// K4: degrees (int fixed-point LDS atomics) -> dis1/dis2; fused h1h = half2(h1*dis1)
__global__ __launch_bounds__(256) void k_deg(
        const uint2* __restrict__ spw, const int* __restrict__ bstart,
        const float* __restrict__ h1,
        float* __restrict__ dis1, float* __restrict__ dis2,
        unsigned* __restrict__ h1h) {
    __shared__ int sdeg[RSZ];
    __shared__ int scnt[RSZ];
    __shared__ float sdis[RSZ];
    int t = threadIdx.x;
    if (t < RSZ) { sdeg[t] = 0; scnt[t] = 0; }
    __syncthreads();
    int s0 = bstart[blockIdx.x], s1 = bstart[blockIdx.x + 1];
    for (int j = s0 + t; j < s1; j += 256) {
        uint2 e = spw[j];
        int lc = e.x >> 17;
        atomicAdd(&sdeg[lc], (int)lrintf(__uint_as_float(e.y) * S_DEG));
        atomicAdd(&scnt[lc], 1);
    }
    __syncthreads();
    int node0 = blockIdx.x * RSZ;
    if (t < RSZ && node0 + t < NN) {
        float d1 = rsqrtf((float)sdeg[t] * INV_S_DEG + 1.f);
        dis1[node0 + t] = d1;
        sdis[t] = d1;
        dis2[node0 + t] = rsqrtf((float)scnt[t] + 1.f);
    }
    __syncthreads();
    for (int i = t; i < RSZ * 8; i += 256) {
        int ln = i >> 3, p = i & 7;
        int node = node0 + ln;
        if (node < NN) {
            float d = sdis[ln];
            __half2 hh = __floats2half2_rn(h1[node * HD + 2 * p] * d,
                                           h1[node * HD + 2 * p + 1] * d);
            h1h[node * 8 + p] = *(unsigned*)&hh;
        }
    }
}

// K5: conv1 aggregate (int fixed-point): acc[c] += h1h[r]*w ; epilogue norm+self+bias
__global__ __launch_bounds__(512) void k_conv1(
        const uint2* __restrict__ spw, const int* __restrict__ bstart,
        const unsigned* __restrict__ h1h, const float* __restrict__ h1,
        const float* __restrict__ dis1, const float* __restrict__ b1,
        float* __restrict__ h1out, unsigned* __restrict__ h1outh) {
    __shared__ int acc[RSZ * ASTRIDE];
    __shared__ float facc[RSZ * ASTRIDE];   // reused for epilogue staging
    int t = threadIdx.x;
    for (int i = t; i < RSZ * ASTRIDE; i += 512) acc[i] = 0;
    __syncthreads();
    int p = t & 7, slot = t >> 3;   // 64 slots x 8 feature-pairs
    int s0 = bstart[blockIdx.x], s1 = bstart[blockIdx.x + 1];
    for (int j = s0 + slot; j < s1; j += 128) {
        // 2-way unroll: issue both gathers before any atomics
        uint2 e0 = spw[j];
        int j1 = j + 64;
        bool has1 = (j1 < s1);
        uint2 e1 = has1 ? spw[j1] : make_uint2(0, 0);
        unsigned g0 = h1h[(e0.x & 0x1FFFF) * 8 + p];
        unsigned g1 = has1 ? h1h[(e1.x & 0x1FFFF) * 8 + p] : 0u;

        float w0 = __uint_as_float(e0.y);
        float2 f0 = __half22float2(*(__half2*)&g0);
        int lc0 = e0.x >> 17;
        atomicAdd(&acc[lc0 * ASTRIDE + 2 * p],     (int)lrintf(f0.x * w0 * S_CONV));
        atomicAdd(&acc[lc0 * ASTRIDE + 2 * p + 1], (int)lrintf(f0.y * w0 * S_CONV));
        if (has1) {
            float w1 = __uint_as_float(e1.y);
            float2 f1 = __half22float2(*(__half2*)&g1);
            int lc1 = e1.x >> 17;
            atomicAdd(&acc[lc1 * ASTRIDE + 2 * p],     (int)lrintf(f1.x * w1 * S_CONV));
            atomicAdd(&acc[lc1 * ASTRIDE + 2 * p + 1], (int)lrintf(f1.y * w1 * S_CONV));
        }
    }
    __syncthreads();
    int node0 = blockIdx.x * RSZ;
    for (int i = t; i < RSZ * HD; i += 512) {
        int ln = i >> 4, ff = i & 15;
        int node = node0 + ln;
        if (node < NN) {
            float d = dis1[node];
            float hv = h1[node * HD + ff];
            float val = (float)acc[ln * ASTRIDE + ff] * INV_S_CONV * d + hv * d * d + b1[ff];
            h1out[node * HD + ff] = val;
            facc[ln * ASTRIDE + ff] = val;
        }
    }
    __syncthreads();
    for (int i = t; i < RSZ * 8; i += 512) {
        int ln = i >> 3, pp = i & 7;
        int node = node0 + ln;
        if (node < NN) {
            __half2 hh = __floats2half2_rn(facc[ln * ASTRIDE + 2 * pp],
                                           facc[ln * ASTRIDE + 2 * pp + 1]);
            h1outh[node * 8 + pp] = *(unsigned*)&hh;
        }
    }
}

// K6: neighbor max pool via monotonic-uint atomicMax in LDS (native)
__global__ __launch_bounds__(512) void k_pool(
        const uint2* __restrict__ spw, const int* __restrict__ bstart,
        const unsigned* __restrict__ h1outh, const float* __restrict__ h1out,
        float* __restrict__ pool) {
    __shared__ unsigned acc[RSZ * ASTRIDE];
    int t = threadIdx.x;
    for (int i = t; i < RSZ * ASTRIDE; i += 512) acc[i] = ENC_NEGINF;
    __syncthreads();
    int p = t & 7, slot = t >> 3;
    int s0 = bstart[blockIdx.x], s1 = bstart[blockIdx.x + 1];
    for (int j = s0 + slot; j < s1; j += 128) {
        unsigned e0 = spw[j].x;
        int j1 = j + 64;
        bool has1 = (j1 < s1);
        unsigned e1 = has1 ? spw[j1].x : 0u;
        unsigned g0 = h1outh[(e0 & 0x1FFFF) * 8 + p];
        unsigned g1 = has1 ? h1outh[(e1 & 0x1FFFF) * 8 + p] : 0u;

        float2 f0 = __half22float2(*(__half2*)&g0);
        int lc0 = e0 >> 17;
        atomicMax(&acc[lc0 * ASTRIDE + 2 * p],     encf(f0.x));
        atomicMax(&acc[lc0 * ASTRIDE + 2 * p + 1], encf(f0.y));
        if (has1) {
            float2 f1 = __half22float2(*(__half2*)&g1);
            int lc1 = e1 >> 17;
            atomicMax(&acc[lc1 * ASTRIDE + 2 * p],     encf(f1.x));
            atomicMax(&acc[lc1 * ASTRIDE + 2 * p + 1], encf(f1.y));
        }
    }
    __syncthreads();
    int node0 = blockIdx.x * RSZ;
    for (int i = t; i < RSZ * HD; i += 512) {
        int ln = i >> 4, ff = i & 15;
        int node = node0 + ln;
        if (node < NN)
            pool[node * HD + ff] = fmaxf(decf(acc[ln * ASTRIDE + ff]),
                                         h1out[node * HD + ff]);
    }
}

// K7: h2s = (pool @ W2) * dis2 (fp32 + fp16 copies)
__global__ __launch_bounds__(256) void k_h2(
        const float* __restrict__ pool, const float* __restrict__ W2,
        const float* __restrict__ dis2,
        float2* __restrict__ h2s, unsigned* __restrict__ h2sh) {
    int t = blockIdx.x * 256 + threadIdx.x;
    if (t >= NN * 8) return;
    int node = t >> 3, p = t & 7;
    float a0 = 0.f, a1 = 0.f;
#pragma unroll
    for (int k = 0; k < HD; ++k) {
        float pv = pool[node * HD + k];
        a0 += pv * W2[k * HD + 2 * p];
        a1 += pv * W2[k * HD + 2 * p + 1];
    }
    float d = dis2[node];
    a0 *= d; a1 *= d;
    h2s[t] = make_float2(a0, a1);
    __half2 hh = __floats2half2_rn(a0, a1);
    h2sh[t] = *(unsigned*)&hh;
}

// K8: conv2 aggregate (int fixed-point) + fused residual-relu epilogue -> hfin
__global__ __launch_bounds__(512) void k_conv2(
        const uint2* __restrict__ spw, const int* __restrict__ bstart,
        const unsigned* __restrict__ h2sh, const float* __restrict__ h2s,
        const float* __restrict__ dis2, const float* __restrict__ pool,
        const float* __restrict__ b2, float* __restrict__ hfin) {
    __shared__ int acc[RSZ * ASTRIDE];
    int t = threadIdx.x;
    for (int i = t; i < RSZ * ASTRIDE; i += 512) acc[i] = 0;
    __syncthreads();
    int p = t & 7, slot = t >> 3;
    int s0 = bstart[blockIdx.x], s1 = bstart[blockIdx.x + 1];
    for (int j = s0 + slot; j < s1; j += 128) {
        unsigned e0 = spw[j].x;
        int j1 = j + 64;
        bool has1 = (j1 < s1);
        unsigned e1 = has1 ? spw[j1].x : 0u;
        unsigned g0 = h2sh[(e0 & 0x1FFFF) * 8 + p];
        unsigned g1 = has1 ? h2sh[(e1 & 0x1FFFF) * 8 + p] : 0u;

        float2 f0 = __half22float2(*(__half2*)&g0);
        int lc0 = e0 >> 17;
        atomicAdd(&acc[lc0 * ASTRIDE + 2 * p],     (int)lrintf(f0.x * S_CONV));
        atomicAdd(&acc[lc0 * ASTRIDE + 2 * p + 1], (int)lrintf(f0.y * S_CONV));
        if (has1) {
            float2 f1 = __half22float2(*(__half2*)&g1);
            int lc1 = e1 >> 17;
            atomicAdd(&acc[lc1 * ASTRIDE + 2 * p],     (int)lrintf(f1.x * S_CONV));
            atomicAdd(&acc[lc1 * ASTRIDE + 2 * p + 1], (int)lrintf(f1.y * S_CONV));
        }
    }
    __syncthreads();
    int node0 = blockIdx.x * RSZ;
    for (int i = t; i < RSZ * HD; i += 512) {
        int ln = i >> 4, ff = i & 15;
        int node = node0 + ln;
        if (node < NN) {
            int idx = node * HD + ff;
            float d = dis2[node];
            float val = pool[idx] + ((float)acc[ln * ASTRIDE + ff] * INV_S_CONV + h2s[idx]) * d + b2[ff];
            hfin[idx] = fmaxf(val, 0.f);
        }
    }
}

// K9: global max pool per graph (batch = (i*G)//N -> contiguous ranges)
__global__ __launch_bounds__(256) void k_graph_max(
        const float* __restrict__ hfin, float* __restrict__ gbuf) {
    int g = blockIdx.x;
    int start = (g * NN + NG - 1) / NG;
    int end   = ((g + 1) * NN + NG - 1) / NG;
    int f = threadIdx.x & 15, sub = threadIdx.x >> 4;
    float m = -3.402823466e38f;
    for (int i = start + sub; i < end; i += 16)
        m = fmaxf(m, hfin[i * HD + f]);
    __shared__ float lds[256];
    lds[threadIdx.x] = m;
    __syncthreads();
    if (threadIdx.x < 16) {
        float mm = lds[threadIdx.x];
#pragma unroll
        for (int s = 1; s < 16; ++s) mm = fmaxf(mm, lds[s * 16 + threadIdx.x]);
        gbuf[g * HD + threadIdx.x] = mm;
    }
}

// K10: head MLP on [G,16]; one thread per graph row
__global__ __launch_bounds__(256) void k_mlp(
        const float* __restrict__ gbuf,
        const float* __restrict__ Wl1, const float* __restrict__ bl1,
        const float* __restrict__ Wl3, const float* __restrict__ bl3,
        const float* __restrict__ Wl4, const float* __restrict__ bl4,
        float* __restrict__ out) {
    __shared__ float sW1[256], sW3[256], sW4[16], sb1[16], sb3[16];
    __shared__ float sb4;
    int tid = threadIdx.x;
    sW1[tid] = Wl1[tid];
    sW3[tid] = Wl3[tid];
    if (tid < 16) { sW4[tid] = Wl4[tid]; sb1[tid] = bl1[tid]; sb3[tid] = bl3[tid]; }
    if (tid == 0) sb4 = bl4[0];
    __syncthreads();

    float v[16], t1[16], t2[16];
#pragma unroll
    for (int f = 0; f < 16; ++f) v[f] = gbuf[tid * 16 + f];
#pragma unroll
    for (int f = 0; f < 16; ++f) {
        float a = sb1[f] + v[f];
#pragma unroll
        for (int k = 0; k < 16; ++k) a += v[k] * sW1[k * 16 + f];
        t1[f] = rrelu_f(a);
    }
#pragma unroll
    for (int f = 0; f < 16; ++f) {
        float a = sb3[f] + t1[f];
#pragma unroll
        for (int k = 0; k < 16; ++k) a += t1[k] * sW3[k * 16 + f];
        t2[f] = rrelu_f(a);
    }
    float o = sb4;
#pragma unroll
    for (int k = 0; k < 16; ++k) o += t2[k] * sW4[k];
    out[tid] = rrelu_f(o);
}

extern "C" void kernel_launch(void* const* d_in, const int* in_sizes, int n_in,
                              void* d_out, int out_size, void* d_ws, size_t ws_size,
                              hipStream_t stream) {
    const float* x   = (const float*)d_in[0];
    const int*   ei  = (const int*)  d_in[1];   // [2, E] flat
    const float* ew  = (const float*)d_in[3];
    const float* W1  = (const float*)d_in[4];
    const float* b1  = (const float*)d_in[5];
    const float* W2  = (const float*)d_in[6];
    const float* b2  = (const float*)d_in[7];
    const float* Wl1 = (const float*)d_in[8];
    const float* bl1 = (const float*)d_in[9];
    const float* Wl3 = (const float*)d_in[10];
    const float* bl3 = (const float*)d_in[11];
    const float* Wl4 = (const float*)d_in[12];
    const float* bl4 = (const float*)d_in[13];
    const int* row = ei;
    const int* col = ei + NE;

    // workspace layout (floats)
    float* ws = (float*)d_ws;
    float* h1    = ws;                     // NN*HD ; reused as hfin after conv1
    float* h1out = h1    + NN * HD;        // NN*HD
    float* pool  = h1out + NN * HD;        // NN*HD ; hist aliases here pre-k_pool
    float* h2s   = pool  + NN * HD;        // NN*HD ; pre aliases here pre-k_h2
    float* dis1  = h2s   + NN * HD;        // NN
    float* dis2  = dis1  + NN;             // NN
    float* gbuf  = dis2  + NN;             // NG*HD
    unsigned* h1h    = (unsigned*)(gbuf + NG * HD);  // NN*8
    unsigned* h1outh = h1h    + NN * 8;              // NN*8
    unsigned* h2sh   = h1outh + NN * 8;              // NN*8
    uint2*    spw    = (uint2*)(h2sh + NN * 8);      // NE uint2
    int* tot    = (int*)(spw + NE);        // NBUK
    int* bstart = tot + NBUK;              // NBUK+1
    int* hist   = (int*)pool;              // FB*NBUK (dead before k_pool writes)
    int* pre    = (int*)h2s;               // NBUK*FB (dead before k_h2 writes)
    float* hfin = h1;

    const int B = 256;

    k_node_prep<<<(NN * HD + B - 1) / B, B, 0, stream>>>(x, W1, h1);
    k_hist     <<<FB, B, 0, stream>>>(col, hist);
    k_scan_a   <<<NBUK, FB, 0, stream>>>(hist, pre, tot);
    k_scan_b   <<<1, 1024, 0, stream>>>(tot, bstart);
    k_fill     <<<FB, B, 0, stream>>>(row, col, ew, pre, bstart, spw);
    k_deg      <<<NBUK, B, 0, stream>>>(spw, bstart, h1, dis1, dis2, h1h);
    k_conv1    <<<NBUK, 512, 0, stream>>>(spw, bstart, h1h, h1, dis1, b1, h1out, h1outh);
    k_pool     <<<NBUK, 512, 0, stream>>>(spw, bstart, h1outh, h1out, pool);
    k_h2       <<<(NN * 8 + B - 1) / B, B, 0, stream>>>(pool, W2, dis2, (float2*)h2s, h2sh);
    k_conv2    <<<NBUK, 512, 0, stream>>>(spw, bstart, h2sh, h2s, dis2, pool, b2, hfin);
    k_graph_max<<<NG, B, 0, stream>>>(hfin, gbuf);
    k_mlp      <<<1, B, 0, stream>>>(gbuf, Wl1, bl1, Wl3, bl3, Wl4, bl4, (float*)d_out);
}

// Round 5
// 283.434 us; speedup vs baseline: 3.8845x; 1.0707x over previous
//
#include <hip/hip_runtime.h>
#include <hip/hip_fp16.h>
#include <math.h>

#define NN 100000
#define NE 3200000
#define NG 256
#define HD 16
#define FIN 7

// Bucketed counting sort parameters
#define RB 7                 // log2(nodes per bucket)
#define RSZ 128              // nodes per bucket
#define NBUK 782             // ceil(NN / RSZ)
#define FB 1024              // fill/hist blocks
#define CHUNK 3125           // NE / FB (exact: 3125*1024 = 3.2M)
#define ASTRIDE 17           // padded u32 LDS accumulator row stride (pool)
#define CSTRIDE 9            // padded u64 LDS accumulator row stride (convs)

// fixed-point: 2^16 scale, 2^25 bias per term; decode exact via int arithmetic
#define S16 65536.0f
#define INV_S16 1.52587890625e-5f
#define IBIAS 33554432u      // 2^25
#define S_DEGW 16777216.0f   // 2^24 for edge-weight degree sums (w in [0,1))
#define INV_S_DEGW 5.9604644775390625e-8f

static constexpr float SLOPE = 0.22916666666666666f;  // eval-mode RReLU mean slope

__device__ __forceinline__ float rrelu_f(float a) {
    return a >= 0.f ? a : SLOPE * a;
}

// monotonic float<->uint encoding for atomicMax-based float max
__device__ __forceinline__ unsigned encf(float v) {
    unsigned u = __float_as_uint(v);
    return u ^ (((unsigned)((int)u >> 31)) | 0x80000000u);
}
__device__ __forceinline__ float decf(unsigned u) {
    unsigned m = ((int)u < 0) ? 0x80000000u : 0xFFFFFFFFu;
    return __uint_as_float(u ^ m);
}
#define ENC_NEGINF 0x00800000u

// ---------------------------------------------------------------------------
// K0: h1 = x @ W1 (fp32)
__global__ __launch_bounds__(256) void k_node_prep(
        const float* __restrict__ x, const float* __restrict__ W1,
        float* __restrict__ h1) {
    int t = blockIdx.x * 256 + threadIdx.x;
    if (t >= NN * HD) return;
    int i = t >> 4, f = t & 15;
    float acc = 0.f;
#pragma unroll
    for (int k = 0; k < FIN; ++k) acc += x[i * FIN + k] * W1[k * HD + f];
    h1[t] = acc;
}

// K1: per-block bucket histogram of col>>RB
__global__ __launch_bounds__(256) void k_hist(
        const int* __restrict__ col, int* __restrict__ hist) {
    __shared__ int bins[NBUK];
    for (int i = threadIdx.x; i < NBUK; i += 256) bins[i] = 0;
    __syncthreads();
    int base = blockIdx.x * CHUNK;
    for (int i = threadIdx.x; i < CHUNK; i += 256)
        atomicAdd(&bins[col[base + i] >> RB], 1);
    __syncthreads();
    for (int i = threadIdx.x; i < NBUK; i += 256)
        hist[blockIdx.x * NBUK + i] = bins[i];
}

// K2a: per-bucket exclusive scan over the FB blocks
__global__ __launch_bounds__(FB) void k_scan_a(
        const int* __restrict__ hist, int* __restrict__ pre, int* __restrict__ tot) {
    __shared__ int s[FB];
    int t = threadIdx.x;
    int v = hist[t * NBUK + blockIdx.x];
    s[t] = v;
    __syncthreads();
    for (int d = 1; d < FB; d <<= 1) {
        int add = (t >= d) ? s[t - d] : 0;
        __syncthreads();
        s[t] += add;
        __syncthreads();
    }
    pre[blockIdx.x * FB + t] = s[t] - v;
    if (t == FB - 1) tot[blockIdx.x] = s[t];
}

// K2b: scan bucket totals -> bstart[0..NBUK]
__global__ __launch_bounds__(1024) void k_scan_b(
        const int* __restrict__ tot, int* __restrict__ bstart) {
    __shared__ int s[1024];
    int t = threadIdx.x;
    int v = (t < NBUK) ? tot[t] : 0;
    s[t] = v;
    __syncthreads();
    for (int d = 1; d < 1024; d <<= 1) {
        int add = (t >= d) ? s[t - d] : 0;
        __syncthreads();
        s[t] += add;
        __syncthreads();
    }
    if (t < NBUK) bstart[t + 1] = s[t];
    if (t == 0) bstart[0] = 0;
}

// K3: fill with LDS staging — block-locally sort chunk into bucket order, then
// write bucket-ordered runs (consecutive staged slots -> consecutive global).
__global__ __launch_bounds__(256) void k_fill(
        const int* __restrict__ row, const int* __restrict__ col,
        const float* __restrict__ ew,
        const int* __restrict__ pre, const int* __restrict__ bstart,
        uint2* __restrict__ spw) {
    __shared__ int lcnt[NBUK];          // counts -> exclusive starts -> alloc walker
    __shared__ int gofs[NBUK];          // lbase -> (lbase - lstart)
    __shared__ int part[256];
    __shared__ unsigned short sbuk[CHUNK];
    __shared__ uint2 stage[CHUNK];
    int t = threadIdx.x;
    for (int i = t; i < NBUK; i += 256) {
        lcnt[i] = 0;
        gofs[i] = bstart[i] + pre[i * FB + blockIdx.x];   // lbase for now
    }
    __syncthreads();
    int base = blockIdx.x * CHUNK;
    for (int i = t; i < CHUNK; i += 256)
        atomicAdd(&lcnt[col[base + i] >> RB], 1);
    __syncthreads();
    // exclusive scan of lcnt[0..NBUK) : 4 buckets per thread + block scan
    int k0 = t * 4;
    int c0 = (k0 + 0 < NBUK) ? lcnt[k0 + 0] : 0;
    int c1 = (k0 + 1 < NBUK) ? lcnt[k0 + 1] : 0;
    int c2 = (k0 + 2 < NBUK) ? lcnt[k0 + 2] : 0;
    int c3 = (k0 + 3 < NBUK) ? lcnt[k0 + 3] : 0;
    int gsum = c0 + c1 + c2 + c3;
    part[t] = gsum;
    __syncthreads();
    for (int d = 1; d < 256; d <<= 1) {
        int add = (t >= d) ? part[t - d] : 0;
        __syncthreads();
        part[t] += add;
        __syncthreads();
    }
    {
        int run = part[t] - gsum;   // exclusive base of this thread's group
        int e0 = run, e1 = run + c0, e2 = e1 + c1, e3 = e2 + c2;
        if (k0 + 0 < NBUK) { gofs[k0 + 0] -= e0; lcnt[k0 + 0] = e0; }
        if (k0 + 1 < NBUK) { gofs[k0 + 1] -= e1; lcnt[k0 + 1] = e1; }
        if (k0 + 2 < NBUK) { gofs[k0 + 2] -= e2; lcnt[k0 + 2] = e2; }
        if (k0 + 3 < NBUK) { gofs[k0 + 3] -= e3; lcnt[k0 + 3] = e3; }
    }
    __syncthreads();
    for (int i = t; i < CHUNK; i += 256) {
        int c = col[base + i];
        int b = c >> RB;
        int s = atomicAdd(&lcnt[b], 1);
        stage[s] = make_uint2(((unsigned)(c & (RSZ - 1)) << 17) | (unsigned)row[base + i],
                              __float_as_uint(ew[base + i]));
        sbuk[s] = (unsigned short)b;
    }
    __syncthreads();
    for (int s = t; s < CHUNK; s += 256)
        spw[s + gofs[sbuk[s]]] = stage[s];
}

// K4: degrees via one packed u64 atomic/edge {count:32 | wsum_fx:32};
// fused h1h = half2(h1 * dis1) prescaled gather copy; cnts for conv decode
__global__ __launch_bounds__(512) void k_deg(
        const uint2* __restrict__ spw, const int* __restrict__ bstart,
        const float* __restrict__ h1,
        float* __restrict__ dis1, float* __restrict__ dis2,
        int* __restrict__ cnts, unsigned* __restrict__ h1h) {
    __shared__ unsigned long long sdeg[RSZ];
    __shared__ float sdis[RSZ];
    int t = threadIdx.x;
    if (t < RSZ) sdeg[t] = 0ULL;
    __syncthreads();
    int s0 = bstart[blockIdx.x], s1 = bstart[blockIdx.x + 1];
    for (int j = s0 + t; j < s1; j += 512) {
        uint2 e = spw[j];
        unsigned qw = (unsigned)lrintf(__uint_as_float(e.y) * S_DEGW);
        atomicAdd(&sdeg[e.x >> 17], (1ULL << 32) | (unsigned long long)qw);
    }
    __syncthreads();
    int node0 = blockIdx.x * RSZ;
    if (t < RSZ && node0 + t < NN) {
        unsigned long long v = sdeg[t];
        unsigned cnt = (unsigned)(v >> 32);
        float wsum = (float)(unsigned)(v & 0xFFFFFFFFULL) * INV_S_DEGW;
        float d1 = rsqrtf(wsum + 1.f);
        dis1[node0 + t] = d1;
        sdis[t] = d1;
        dis2[node0 + t] = rsqrtf((float)cnt + 1.f);
        cnts[node0 + t] = (int)cnt;
    }
    __syncthreads();
    for (int i = t; i < RSZ * 8; i += 512) {
        int ln = i >> 3, p = i & 7;
        int node = node0 + ln;
        if (node < NN) {
            float d = sdis[ln];
            __half2 hh = __floats2half2_rn(h1[node * HD + 2 * p] * d,
                                           h1[node * HD + 2 * p + 1] * d);
            h1h[node * 8 + p] = *(unsigned*)&hh;
        }
    }
}

// K5: conv1 aggregate with packed u64 fixed-point atomics (2 features/atomic)
__global__ __launch_bounds__(512) void k_conv1(
        const uint2* __restrict__ spw, const int* __restrict__ bstart,
        const unsigned* __restrict__ h1h, const float* __restrict__ h1,
        const float* __restrict__ dis1, const int* __restrict__ cnts,
        const float* __restrict__ b1, unsigned* __restrict__ h1outh) {
    __shared__ unsigned long long acc[RSZ * CSTRIDE];
    int t = threadIdx.x;
    for (int i = t; i < RSZ * CSTRIDE; i += 512) acc[i] = 0ULL;
    __syncthreads();
    int p = t & 7, slot = t >> 3;   // 64 slots x 8 feature-pairs
    int s0 = bstart[blockIdx.x], s1 = bstart[blockIdx.x + 1];
    for (int j = s0 + slot; j < s1; j += 128) {
        uint2 e0 = spw[j];
        int j1 = j + 64;
        bool has1 = (j1 < s1);
        uint2 e1 = has1 ? spw[j1] : make_uint2(0, 0);
        unsigned g0 = h1h[(e0.x & 0x1FFFF) * 8 + p];
        unsigned g1 = has1 ? h1h[(e1.x & 0x1FFFF) * 8 + p] : 0u;
        {
            float w = __uint_as_float(e0.y);
            float2 f = __half22float2(*(__half2*)&g0);
            unsigned q0 = (unsigned)(int)lrintf(f.x * w * S16) + IBIAS;
            unsigned q1 = (unsigned)(int)lrintf(f.y * w * S16) + IBIAS;
            atomicAdd(&acc[(e0.x >> 17) * CSTRIDE + p],
                      ((unsigned long long)q0 << 32) | (unsigned long long)q1);
        }
        if (has1) {
            float w = __uint_as_float(e1.y);
            float2 f = __half22float2(*(__half2*)&g1);
            unsigned q0 = (unsigned)(int)lrintf(f.x * w * S16) + IBIAS;
            unsigned q1 = (unsigned)(int)lrintf(f.y * w * S16) + IBIAS;
            atomicAdd(&acc[(e1.x >> 17) * CSTRIDE + p],
                      ((unsigned long long)q0 << 32) | (unsigned long long)q1);
        }
    }
    __syncthreads();
    int node0 = blockIdx.x * RSZ;
    for (int i = t; i < RSZ * 8; i += 512) {
        int ln = i >> 3, pp = i & 7;
        int node = node0 + ln;
        if (node < NN) {
            unsigned long long v = acc[ln * CSTRIDE + pp];
            unsigned kb = (unsigned)cnts[node] * IBIAS;   // mod-2^32 exact decode
            float a0 = (float)(int)((unsigned)(v >> 32) - kb) * INV_S16;
            float a1 = (float)(int)((unsigned)(v & 0xFFFFFFFFULL) - kb) * INV_S16;
            float d = dis1[node];
            float hv0 = h1[node * HD + 2 * pp];
            float hv1 = h1[node * HD + 2 * pp + 1];
            float r0 = a0 * d + hv0 * d * d + b1[2 * pp];
            float r1 = a1 * d + hv1 * d * d + b1[2 * pp + 1];
            __half2 hh = __floats2half2_rn(r0, r1);
            h1outh[node * 8 + pp] = *(unsigned*)&hh;
        }
    }
}

// K6: neighbor max pool via monotonic-uint atomicMax in LDS; self from fp16 copy
__global__ __launch_bounds__(512) void k_pool(
        const uint2* __restrict__ spw, const int* __restrict__ bstart,
        const unsigned* __restrict__ h1outh, float2* __restrict__ pool2) {
    __shared__ unsigned acc[RSZ * ASTRIDE];
    int t = threadIdx.x;
    for (int i = t; i < RSZ * ASTRIDE; i += 512) acc[i] = ENC_NEGINF;
    __syncthreads();
    int p = t & 7, slot = t >> 3;
    int s0 = bstart[blockIdx.x], s1 = bstart[blockIdx.x + 1];
    for (int j = s0 + slot; j < s1; j += 128) {
        unsigned e0 = spw[j].x;
        int j1 = j + 64;
        bool has1 = (j1 < s1);
        unsigned e1 = has1 ? spw[j1].x : 0u;
        unsigned g0 = h1outh[(e0 & 0x1FFFF) * 8 + p];
        unsigned g1 = has1 ? h1outh[(e1 & 0x1FFFF) * 8 + p] : 0u;
        {
            float2 f = __half22float2(*(__half2*)&g0);
            int lc = e0 >> 17;
            atomicMax(&acc[lc * ASTRIDE + 2 * p],     encf(f.x));
            atomicMax(&acc[lc * ASTRIDE + 2 * p + 1], encf(f.y));
        }
        if (has1) {
            float2 f = __half22float2(*(__half2*)&g1);
            int lc = e1 >> 17;
            atomicMax(&acc[lc * ASTRIDE + 2 * p],     encf(f.x));
            atomicMax(&acc[lc * ASTRIDE + 2 * p + 1], encf(f.y));
        }
    }
    __syncthreads();
    int node0 = blockIdx.x * RSZ;
    for (int i = t; i < RSZ * 8; i += 512) {
        int ln = i >> 3, pp = i & 7;
        int node = node0 + ln;
        if (node < NN) {
            unsigned sh = h1outh[node * 8 + pp];
            float2 sf = __half22float2(*(__half2*)&sh);
            pool2[node * 8 + pp] = make_float2(
                fmaxf(decf(acc[ln * ASTRIDE + 2 * pp]),     sf.x),
                fmaxf(decf(acc[ln * ASTRIDE + 2 * pp + 1]), sf.y));
        }
    }
}

// K7: h2s = (pool @ W2) * dis2 (fp32 + fp16 copies)
__global__ __launch_bounds__(256) void k_h2(
        const float* __restrict__ pool, const float* __restrict__ W2,
        const float* __restrict__ dis2,
        float2* __restrict__ h2s, unsigned* __restrict__ h2sh) {
    int t = blockIdx.x * 256 + threadIdx.x;
    if (t >= NN * 8) return;
    int node = t >> 3, p = t & 7;
    float a0 = 0.f, a1 = 0.f;
#pragma unroll
    for (int k = 0; k < HD; ++k) {
        float pv = pool[node * HD + k];
        a0 += pv * W2[k * HD + 2 * p];
        a1 += pv * W2[k * HD + 2 * p + 1];
    }
    float d = dis2[node];
    a0 *= d; a1 *= d;
    h2s[t] = make_float2(a0, a1);
    __half2 hh = __floats2half2_rn(a0, a1);
    h2sh[t] = *(unsigned*)&hh;
}

// K8: conv2 aggregate (packed u64) + fused residual-relu epilogue -> hfin
__global__ __launch_bounds__(512) void k_conv2(
        const uint2* __restrict__ spw, const int* __restrict__ bstart,
        const unsigned* __restrict__ h2sh, const float2* __restrict__ h2s,
        const float* __restrict__ dis2, const int* __restrict__ cnts,
        const float2* __restrict__ pool2, const float* __restrict__ b2,
        float2* __restrict__ hfin2) {
    __shared__ unsigned long long acc[RSZ * CSTRIDE];
    int t = threadIdx.x;
    for (int i = t; i < RSZ * CSTRIDE; i += 512) acc[i] = 0ULL;
    __syncthreads();
    int p = t & 7, slot = t >> 3;
    int s0 = bstart[blockIdx.x], s1 = bstart[blockIdx.x + 1];
    for (int j = s0 + slot; j < s1; j += 128) {
        unsigned e0 = spw[j].x;
        int j1 = j + 64;
        bool has1 = (j1 < s1);
        unsigned e1 = has1 ? spw[j1].x : 0u;
        unsigned g0 = h2sh[(e0 & 0x1FFFF) * 8 + p];
        unsigned g1 = has1 ? h2sh[(e1 & 0x1FFFF) * 8 + p] : 0u;
        {
            float2 f = __half22float2(*(__half2*)&g0);
            unsigned q0 = (unsigned)(int)lrintf(f.x * S16) + IBIAS;
            unsigned q1 = (unsigned)(int)lrintf(f.y * S16) + IBIAS;
            atomicAdd(&acc[(e0 >> 17) * CSTRIDE + p],
                      ((unsigned long long)q0 << 32) | (unsigned long long)q1);
        }
        if (has1) {
            float2 f = __half22float2(*(__half2*)&g1);
            unsigned q0 = (unsigned)(int)lrintf(f.x * S16) + IBIAS;
            unsigned q1 = (unsigned)(int)lrintf(f.y * S16) + IBIAS;
            atomicAdd(&acc[(e1 >> 17) * CSTRIDE + p],
                      ((unsigned long long)q0 << 32) | (unsigned long long)q1);
        }
    }
    __syncthreads();
    int node0 = blockIdx.x * RSZ;
    for (int i = t; i < RSZ * 8; i += 512) {
        int ln = i >> 3, pp = i & 7;
        int node = node0 + ln;
        if (node < NN) {
            unsigned long long v = acc[ln * CSTRIDE + pp];
            unsigned kb = (unsigned)cnts[node] * IBIAS;
            float a0 = (float)(int)((unsigned)(v >> 32) - kb) * INV_S16;
            float a1 = (float)(int)((unsigned)(v & 0xFFFFFFFFULL) - kb) * INV_S16;
            float d = dis2[node];
            float2 self = h2s[node * 8 + pp];
            float2 pl = pool2[node * 8 + pp];
            float r0 = pl.x + (a0 + self.x) * d + b2[2 * pp];
            float r1 = pl.y + (a1 + self.y) * d + b2[2 * pp + 1];
            hfin2[node * 8 + pp] = make_float2(fmaxf(r0, 0.f), fmaxf(r1, 0.f));
        }
    }
}

// K9: global max pool per graph (batch = (i*G)//N -> contiguous ranges)
__global__ __launch_bounds__(256) void k_graph_max(
        const float* __restrict__ hfin, float* __restrict__ gbuf) {
    int g = blockIdx.x;
    int start = (g * NN + NG - 1) / NG;
    int end   = ((g + 1) * NN + NG - 1) / NG;
    int f = threadIdx.x & 15, sub = threadIdx.x >> 4;
    float m = -3.402823466e38f;
    for (int i = start + sub; i < end; i += 16)
        m = fmaxf(m, hfin[i * HD + f]);
    __shared__ float lds[256];
    lds[threadIdx.x] = m;
    __syncthreads();
    if (threadIdx.x < 16) {
        float mm = lds[threadIdx.x];
#pragma unroll
        for (int s = 1; s < 16; ++s) mm = fmaxf(mm, lds[s * 16 + threadIdx.x]);
        gbuf[g * HD + threadIdx.x] = mm;
    }
}

// K10: head MLP on [G,16]; one thread per graph row
__global__ __launch_bounds__(256) void k_mlp(
        const float* __restrict__ gbuf,
        const float* __restrict__ Wl1, const float* __restrict__ bl1,
        const float* __restrict__ Wl3, const float* __restrict__ bl3,
        const float* __restrict__ Wl4, const float* __restrict__ bl4,
        float* __restrict__ out) {
    __shared__ float sW1[256], sW3[256], sW4[16], sb1[16], sb3[16];
    __shared__ float sb4;
    int tid = threadIdx.x;
    sW1[tid] = Wl1[tid];
    sW3[tid] = Wl3[tid];
    if (tid < 16) { sW4[tid] = Wl4[tid]; sb1[tid] = bl1[tid]; sb3[tid] = bl3[tid]; }
    if (tid == 0) sb4 = bl4[0];
    __syncthreads();

    float v[16], t1[16], t2[16];
#pragma unroll
    for (int f = 0; f < 16; ++f) v[f] = gbuf[tid * 16 + f];
#pragma unroll
    for (int f = 0; f < 16; ++f) {
        float a = sb1[f] + v[f];
#pragma unroll
        for (int k = 0; k < 16; ++k) a += v[k] * sW1[k * 16 + f];
        t1[f] = rrelu_f(a);
    }
#pragma unroll
    for (int f = 0; f < 16; ++f) {
        float a = sb3[f] + t1[f];
#pragma unroll
        for (int k = 0; k < 16; ++k) a += t1[k] * sW3[k * 16 + f];
        t2[f] = rrelu_f(a);
    }
    float o = sb4;
#pragma unroll
    for (int k = 0; k < 16; ++k) o += t2[k] * sW4[k];
    out[tid] = rrelu_f(o);
}

extern "C" void kernel_launch(void* const* d_in, const int* in_sizes, int n_in,
                              void* d_out, int out_size, void* d_ws, size_t ws_size,
                              hipStream_t stream) {
    const float* x   = (const float*)d_in[0];
    const int*   ei  = (const int*)  d_in[1];   // [2, E] flat
    const float* ew  = (const float*)d_in[3];
    const float* W1  = (const float*)d_in[4];
    const float* b1  = (const float*)d_in[5];
    const float* W2  = (const float*)d_in[6];
    const float* b2  = (const float*)d_in[7];
    const float* Wl1 = (const float*)d_in[8];
    const float* bl1 = (const float*)d_in[9];
    const float* Wl3 = (const float*)d_in[10];
    const float* bl3 = (const float*)d_in[11];
    const float* Wl4 = (const float*)d_in[12];
    const float* bl4 = (const float*)d_in[13];
    const int* row = ei;
    const int* col = ei + NE;

    // workspace layout (floats)
    float* ws = (float*)d_ws;
    float* h1    = ws;                     // NN*HD ; hfin reuses this after conv1
    float* pool  = h1   + NN * HD;         // NN*HD ; hist aliases here pre-k_pool
    float* h2s   = pool + NN * HD;         // NN*HD ; pre aliases here pre-k_h2
    float* dis1  = h2s  + NN * HD;         // NN
    float* dis2  = dis1 + NN;              // NN
    int*   cnts  = (int*)(dis2 + NN);      // NN
    float* gbuf  = (float*)(cnts + NN);    // NG*HD
    unsigned* h1h    = (unsigned*)(gbuf + NG * HD);  // NN*8
    unsigned* h1outh = h1h    + NN * 8;              // NN*8
    unsigned* h2sh   = h1outh + NN * 8;              // NN*8
    uint2*    spw    = (uint2*)(h2sh + NN * 8);      // NE uint2
    int* tot    = (int*)(spw + NE);        // NBUK
    int* bstart = tot + NBUK;              // NBUK+1
    int* hist   = (int*)pool;              // FB*NBUK (3.2MB, dead before k_pool)
    int* pre    = (int*)h2s;               // NBUK*FB (3.2MB, dead before k_h2)
    float* hfin = h1;

    const int B = 256;

    k_node_prep<<<(NN * HD + B - 1) / B, B, 0, stream>>>(x, W1, h1);
    k_hist     <<<FB, B, 0, stream>>>(col, hist);
    k_scan_a   <<<NBUK, FB, 0, stream>>>(hist, pre, tot);
    k_scan_b   <<<1, 1024, 0, stream>>>(tot, bstart);
    k_fill     <<<FB, B, 0, stream>>>(row, col, ew, pre, bstart, spw);
    k_deg      <<<NBUK, 512, 0, stream>>>(spw, bstart, h1, dis1, dis2, cnts, h1h);
    k_conv1    <<<NBUK, 512, 0, stream>>>(spw, bstart, h1h, h1, dis1, cnts, b1, h1outh);
    k_pool     <<<NBUK, 512, 0, stream>>>(spw, bstart, h1outh, (float2*)pool);
    k_h2       <<<(NN * 8 + B - 1) / B, B, 0, stream>>>(pool, W2, dis2, (float2*)h2s, h2sh);
    k_conv2    <<<NBUK, 512, 0, stream>>>(spw, bstart, h2sh, (const float2*)h2s, dis2,
                                          cnts, (const float2*)pool, b2, (float2*)hfin);
    k_graph_max<<<NG, B, 0, stream>>>(hfin, gbuf);
    k_mlp      <<<1, B, 0, stream>>>(gbuf, Wl1, bl1, Wl3, bl3, Wl4, bl4, (float*)d_out);
}

// Round 6
// 266.417 us; speedup vs baseline: 4.1326x; 1.0639x over previous
//
#include <hip/hip_runtime.h>
#include <hip/hip_fp16.h>
#include <math.h>

#define NN 100000
#define NE 3200000
#define NG 256
#define HD 16
#define FIN 7

// Bucketed counting sort parameters
#define RB 8                 // log2(nodes per bucket)
#define RSZ 256              // nodes per bucket
#define NBUK 391             // ceil(NN / RSZ) ; 391*256 = 100096
#define FB 1024              // fill/hist blocks
#define CHUNK 3125           // NE / FB (exact)
#define ASTRIDE 17           // padded u32 LDS accumulator row stride (pool)
#define CSTRIDE 9            // padded u64 LDS accumulator row stride (convs)
#define LMASK 0x1FFFF        // row mask (17 bits)

// fixed-point: 2^16 scale, 2^25 bias per term; exact mod-2^32 decode
#define S16 65536.0f
#define INV_S16 1.52587890625e-5f
#define IBIAS 33554432u      // 2^25
#define S_DEGW 16777216.0f   // 2^24 for edge-weight degree sums (w in [0,1))
#define INV_S_DEGW 5.9604644775390625e-8f

static constexpr float SLOPE = 0.22916666666666666f;  // eval-mode RReLU mean slope

__device__ __forceinline__ float rrelu_f(float a) {
    return a >= 0.f ? a : SLOPE * a;
}

// monotonic float<->uint encoding for atomicMax-based float max
__device__ __forceinline__ unsigned encf(float v) {
    unsigned u = __float_as_uint(v);
    return u ^ (((unsigned)((int)u >> 31)) | 0x80000000u);
}
__device__ __forceinline__ float decf(unsigned u) {
    unsigned m = ((int)u < 0) ? 0x80000000u : 0xFFFFFFFFu;
    return __uint_as_float(u ^ m);
}
#define ENC_NEGINF 0x00800000u

// ---------------------------------------------------------------------------
// K0: h1 = x @ W1 (fp32)
__global__ __launch_bounds__(256) void k_node_prep(
        const float* __restrict__ x, const float* __restrict__ W1,
        float* __restrict__ h1) {
    int t = blockIdx.x * 256 + threadIdx.x;
    if (t >= NN * HD) return;
    int i = t >> 4, f = t & 15;
    float acc = 0.f;
#pragma unroll
    for (int k = 0; k < FIN; ++k) acc += x[i * FIN + k] * W1[k * HD + f];
    h1[t] = acc;
}

// K1: per-block bucket histogram of col>>RB
__global__ __launch_bounds__(256) void k_hist(
        const int* __restrict__ col, int* __restrict__ hist) {
    __shared__ int bins[NBUK];
    for (int i = threadIdx.x; i < NBUK; i += 256) bins[i] = 0;
    __syncthreads();
    int base = blockIdx.x * CHUNK;
    for (int i = threadIdx.x; i < CHUNK; i += 256)
        atomicAdd(&bins[col[base + i] >> RB], 1);
    __syncthreads();
    for (int i = threadIdx.x; i < NBUK; i += 256)
        hist[blockIdx.x * NBUK + i] = bins[i];
}

// K2a: per-bucket exclusive scan over the FB blocks
__global__ __launch_bounds__(FB) void k_scan_a(
        const int* __restrict__ hist, int* __restrict__ pre, int* __restrict__ tot) {
    __shared__ int s[FB];
    int t = threadIdx.x;
    int v = hist[t * NBUK + blockIdx.x];
    s[t] = v;
    __syncthreads();
    for (int d = 1; d < FB; d <<= 1) {
        int add = (t >= d) ? s[t - d] : 0;
        __syncthreads();
        s[t] += add;
        __syncthreads();
    }
    pre[blockIdx.x * FB + t] = s[t] - v;
    if (t == FB - 1) tot[blockIdx.x] = s[t];
}

// K2b: scan bucket totals -> bstart[0..NBUK]
__global__ __launch_bounds__(512) void k_scan_b(
        const int* __restrict__ tot, int* __restrict__ bstart) {
    __shared__ int s[512];
    int t = threadIdx.x;
    int v = (t < NBUK) ? tot[t] : 0;
    s[t] = v;
    __syncthreads();
    for (int d = 1; d < 512; d <<= 1) {
        int add = (t >= d) ? s[t - d] : 0;
        __syncthreads();
        s[t] += add;
        __syncthreads();
    }
    if (t < NBUK) bstart[t + 1] = s[t];
    if (t == 0) bstart[0] = 0;
}

// K3: fill with LDS staging — block-locally sort chunk into bucket order, then
// write bucket-ordered runs (consecutive staged slots -> consecutive global).
__global__ __launch_bounds__(256) void k_fill(
        const int* __restrict__ row, const int* __restrict__ col,
        const float* __restrict__ ew,
        const int* __restrict__ pre, const int* __restrict__ bstart,
        uint2* __restrict__ spw) {
    __shared__ int lcnt[NBUK];          // counts -> exclusive starts -> alloc walker
    __shared__ int gofs[NBUK];          // lbase -> (lbase - lstart)
    __shared__ int part[256];
    __shared__ unsigned short sbuk[CHUNK];
    __shared__ uint2 stage[CHUNK];
    int t = threadIdx.x;
    for (int i = t; i < NBUK; i += 256) {
        lcnt[i] = 0;
        gofs[i] = bstart[i] + pre[i * FB + blockIdx.x];   // lbase for now
    }
    __syncthreads();
    int base = blockIdx.x * CHUNK;
    for (int i = t; i < CHUNK; i += 256)
        atomicAdd(&lcnt[col[base + i] >> RB], 1);
    __syncthreads();
    // exclusive scan of lcnt[0..NBUK): 2 buckets/thread + block scan over 256
    int k0 = t * 2;
    int c0 = (k0 + 0 < NBUK) ? lcnt[k0 + 0] : 0;
    int c1 = (k0 + 1 < NBUK) ? lcnt[k0 + 1] : 0;
    int gsum = c0 + c1;
    part[t] = gsum;
    __syncthreads();
    for (int d = 1; d < 256; d <<= 1) {
        int add = (t >= d) ? part[t - d] : 0;
        __syncthreads();
        part[t] += add;
        __syncthreads();
    }
    {
        int run = part[t] - gsum;   // exclusive base of this thread's pair
        int e0 = run, e1 = run + c0;
        if (k0 + 0 < NBUK) { gofs[k0 + 0] -= e0; lcnt[k0 + 0] = e0; }
        if (k0 + 1 < NBUK) { gofs[k0 + 1] -= e1; lcnt[k0 + 1] = e1; }
    }
    __syncthreads();
    for (int i = t; i < CHUNK; i += 256) {
        int c = col[base + i];
        int b = c >> RB;
        int s = atomicAdd(&lcnt[b], 1);
        stage[s] = make_uint2(((unsigned)(c & (RSZ - 1)) << 17) | (unsigned)row[base + i],
                              __float_as_uint(ew[base + i]));
        sbuk[s] = (unsigned short)b;
    }
    __syncthreads();
    for (int s = t; s < CHUNK; s += 256)
        spw[s + gofs[sbuk[s]]] = stage[s];
}

// K4: degrees via one packed u64 atomic/edge {count:32 | wsum_fx:32};
// fused h1h = half2(h1 * dis1) prescaled gather copy; cnts for conv decode
__global__ __launch_bounds__(1024) void k_deg(
        const uint2* __restrict__ spw, const int* __restrict__ bstart,
        const float* __restrict__ h1,
        float* __restrict__ dis1, float* __restrict__ dis2,
        int* __restrict__ cnts, unsigned* __restrict__ h1h) {
    __shared__ unsigned long long sdeg[RSZ];
    __shared__ float sdis[RSZ];
    int t = threadIdx.x;
    if (t < RSZ) sdeg[t] = 0ULL;
    __syncthreads();
    int s0 = bstart[blockIdx.x], s1 = bstart[blockIdx.x + 1];
    int j = s0 + t;
    for (; j + 3072 < s1; j += 4096) {
        uint2 e0 = spw[j], e1 = spw[j + 1024], e2 = spw[j + 2048], e3 = spw[j + 3072];
        atomicAdd(&sdeg[e0.x >> 17], (1ULL << 32) |
                  (unsigned long long)(unsigned)__float2int_rn(__uint_as_float(e0.y) * S_DEGW));
        atomicAdd(&sdeg[e1.x >> 17], (1ULL << 32) |
                  (unsigned long long)(unsigned)__float2int_rn(__uint_as_float(e1.y) * S_DEGW));
        atomicAdd(&sdeg[e2.x >> 17], (1ULL << 32) |
                  (unsigned long long)(unsigned)__float2int_rn(__uint_as_float(e2.y) * S_DEGW));
        atomicAdd(&sdeg[e3.x >> 17], (1ULL << 32) |
                  (unsigned long long)(unsigned)__float2int_rn(__uint_as_float(e3.y) * S_DEGW));
    }
    for (; j < s1; j += 1024) {
        uint2 e = spw[j];
        atomicAdd(&sdeg[e.x >> 17], (1ULL << 32) |
                  (unsigned long long)(unsigned)__float2int_rn(__uint_as_float(e.y) * S_DEGW));
    }
    __syncthreads();
    int node0 = blockIdx.x * RSZ;
    if (t < RSZ && node0 + t < NN) {
        unsigned long long v = sdeg[t];
        unsigned cnt = (unsigned)(v >> 32);
        float wsum = (float)(unsigned)(v & 0xFFFFFFFFULL) * INV_S_DEGW;
        float d1 = rsqrtf(wsum + 1.f);
        dis1[node0 + t] = d1;
        sdis[t] = d1;
        dis2[node0 + t] = rsqrtf((float)cnt + 1.f);
        cnts[node0 + t] = (int)cnt;
    }
    __syncthreads();
    for (int i = t; i < RSZ * 8; i += 1024) {
        int ln = i >> 3, p = i & 7;
        int node = node0 + ln;
        if (node < NN) {
            float d = sdis[ln];
            __half2 hh = __floats2half2_rn(h1[node * HD + 2 * p] * d,
                                           h1[node * HD + 2 * p + 1] * d);
            h1h[node * 8 + p] = *(unsigned*)&hh;
        }
    }
}

__device__ __forceinline__ void conv_acc(unsigned long long* acc, unsigned ex,
                                         unsigned g, float w, int p) {
    float2 f = __half22float2(*(__half2*)&g);
    unsigned q0 = (unsigned)__float2int_rn(f.x * w) + IBIAS;
    unsigned q1 = (unsigned)__float2int_rn(f.y * w) + IBIAS;
    atomicAdd(&acc[(ex >> 17) * CSTRIDE + p],
              ((unsigned long long)q0 << 32) | (unsigned long long)q1);
}

// K5: conv1 aggregate with packed u64 fixed-point atomics (2 features/atomic)
__global__ __launch_bounds__(1024) void k_conv1(
        const uint2* __restrict__ spw, const int* __restrict__ bstart,
        const unsigned* __restrict__ h1h, const float* __restrict__ h1,
        const float* __restrict__ dis1, const int* __restrict__ cnts,
        const float* __restrict__ b1, unsigned* __restrict__ h1outh) {
    __shared__ unsigned long long acc[RSZ * CSTRIDE];
    int t = threadIdx.x;
    for (int i = t; i < RSZ * CSTRIDE; i += 1024) acc[i] = 0ULL;
    __syncthreads();
    int p = t & 7, slot = t >> 3;   // 128 slots x 8 feature-pairs
    int s0 = bstart[blockIdx.x], s1 = bstart[blockIdx.x + 1];
    int j = s0 + slot;
    for (; j + 384 < s1; j += 512) {
        uint2 e0 = spw[j], e1 = spw[j + 128], e2 = spw[j + 256], e3 = spw[j + 384];
        unsigned g0 = h1h[(e0.x & LMASK) * 8 + p];
        unsigned g1 = h1h[(e1.x & LMASK) * 8 + p];
        unsigned g2 = h1h[(e2.x & LMASK) * 8 + p];
        unsigned g3 = h1h[(e3.x & LMASK) * 8 + p];
        conv_acc(acc, e0.x, g0, __uint_as_float(e0.y) * S16, p);
        conv_acc(acc, e1.x, g1, __uint_as_float(e1.y) * S16, p);
        conv_acc(acc, e2.x, g2, __uint_as_float(e2.y) * S16, p);
        conv_acc(acc, e3.x, g3, __uint_as_float(e3.y) * S16, p);
    }
    for (; j < s1; j += 128) {
        uint2 e = spw[j];
        unsigned g = h1h[(e.x & LMASK) * 8 + p];
        conv_acc(acc, e.x, g, __uint_as_float(e.y) * S16, p);
    }
    __syncthreads();
    int node0 = blockIdx.x * RSZ;
    for (int i = t; i < RSZ * 8; i += 1024) {
        int ln = i >> 3, pp = i & 7;
        int node = node0 + ln;
        if (node < NN) {
            unsigned long long v = acc[ln * CSTRIDE + pp];
            unsigned kb = (unsigned)cnts[node] * IBIAS;   // mod-2^32 exact decode
            float a0 = (float)(int)((unsigned)(v >> 32) - kb) * INV_S16;
            float a1 = (float)(int)((unsigned)(v & 0xFFFFFFFFULL) - kb) * INV_S16;
            float d = dis1[node];
            float r0 = a0 * d + h1[node * HD + 2 * pp] * d * d + b1[2 * pp];
            float r1 = a1 * d + h1[node * HD + 2 * pp + 1] * d * d + b1[2 * pp + 1];
            __half2 hh = __floats2half2_rn(r0, r1);
            h1outh[node * 8 + pp] = *(unsigned*)&hh;
        }
    }
}

// K6: neighbor max pool (monotonic-uint atomicMax) + FUSED h2 = (pool@W2)*dis2
__global__ __launch_bounds__(1024) void k_pool_h2(
        const uint2* __restrict__ spw, const int* __restrict__ bstart,
        const unsigned* __restrict__ h1outh, const float* __restrict__ W2,
        const float* __restrict__ dis2,
        float2* __restrict__ pool2, float2* __restrict__ h2s,
        unsigned* __restrict__ h2sh) {
    __shared__ unsigned acc[RSZ * ASTRIDE];
    __shared__ float sW2[256];
    int t = threadIdx.x;
    if (t < 256) sW2[t] = W2[t];
    for (int i = t; i < RSZ * ASTRIDE; i += 1024) acc[i] = ENC_NEGINF;
    __syncthreads();
    int p = t & 7, slot = t >> 3;
    int s0 = bstart[blockIdx.x], s1 = bstart[blockIdx.x + 1];
    int j = s0 + slot;
    for (; j + 384 < s1; j += 512) {
        unsigned e0 = spw[j].x, e1 = spw[j + 128].x, e2 = spw[j + 256].x, e3 = spw[j + 384].x;
        unsigned g0 = h1outh[(e0 & LMASK) * 8 + p];
        unsigned g1 = h1outh[(e1 & LMASK) * 8 + p];
        unsigned g2 = h1outh[(e2 & LMASK) * 8 + p];
        unsigned g3 = h1outh[(e3 & LMASK) * 8 + p];
        float2 f;
        f = __half22float2(*(__half2*)&g0);
        atomicMax(&acc[(e0 >> 17) * ASTRIDE + 2 * p], encf(f.x));
        atomicMax(&acc[(e0 >> 17) * ASTRIDE + 2 * p + 1], encf(f.y));
        f = __half22float2(*(__half2*)&g1);
        atomicMax(&acc[(e1 >> 17) * ASTRIDE + 2 * p], encf(f.x));
        atomicMax(&acc[(e1 >> 17) * ASTRIDE + 2 * p + 1], encf(f.y));
        f = __half22float2(*(__half2*)&g2);
        atomicMax(&acc[(e2 >> 17) * ASTRIDE + 2 * p], encf(f.x));
        atomicMax(&acc[(e2 >> 17) * ASTRIDE + 2 * p + 1], encf(f.y));
        f = __half22float2(*(__half2*)&g3);
        atomicMax(&acc[(e3 >> 17) * ASTRIDE + 2 * p], encf(f.x));
        atomicMax(&acc[(e3 >> 17) * ASTRIDE + 2 * p + 1], encf(f.y));
    }
    for (; j < s1; j += 128) {
        unsigned e = spw[j].x;
        unsigned g = h1outh[(e & LMASK) * 8 + p];
        float2 f = __half22float2(*(__half2*)&g);
        atomicMax(&acc[(e >> 17) * ASTRIDE + 2 * p], encf(f.x));
        atomicMax(&acc[(e >> 17) * ASTRIDE + 2 * p + 1], encf(f.y));
    }
    __syncthreads();
    int node0 = blockIdx.x * RSZ;
    // epilogue 1: pool = max(agg, self); write pool2; stash pool floats in acc
    for (int i = t; i < RSZ * 8; i += 1024) {
        int ln = i >> 3, pp = i & 7;
        int node = node0 + ln;
        if (node < NN) {
            unsigned sh = h1outh[node * 8 + pp];
            float2 sf = __half22float2(*(__half2*)&sh);
            float m0 = fmaxf(decf(acc[ln * ASTRIDE + 2 * pp]),     sf.x);
            float m1 = fmaxf(decf(acc[ln * ASTRIDE + 2 * pp + 1]), sf.y);
            pool2[node * 8 + pp] = make_float2(m0, m1);
            acc[ln * ASTRIDE + 2 * pp]     = __float_as_uint(m0);
            acc[ln * ASTRIDE + 2 * pp + 1] = __float_as_uint(m1);
        }
    }
    __syncthreads();
    // epilogue 2 (fused k_h2): h2s = (pool @ W2) * dis2, fp32 + fp16 copies
    for (int i = t; i < RSZ * 8; i += 1024) {
        int ln = i >> 3, pp = i & 7;
        int node = node0 + ln;
        if (node < NN) {
            float a0 = 0.f, a1 = 0.f;
#pragma unroll
            for (int k = 0; k < HD; ++k) {
                float pv = __uint_as_float(acc[ln * ASTRIDE + k]);
                a0 += pv * sW2[k * HD + 2 * pp];
                a1 += pv * sW2[k * HD + 2 * pp + 1];
            }
            float d = dis2[node];
            a0 *= d; a1 *= d;
            h2s[node * 8 + pp] = make_float2(a0, a1);
            __half2 hh = __floats2half2_rn(a0, a1);
            h2sh[node * 8 + pp] = *(unsigned*)&hh;
        }
    }
}

// K8: conv2 aggregate (packed u64) + fused residual-relu epilogue -> hfin
__global__ __launch_bounds__(1024) void k_conv2(
        const uint2* __restrict__ spw, const int* __restrict__ bstart,
        const unsigned* __restrict__ h2sh, const float2* __restrict__ h2s,
        const float* __restrict__ dis2, const int* __restrict__ cnts,
        const float2* __restrict__ pool2, const float* __restrict__ b2,
        float2* __restrict__ hfin2) {
    __shared__ unsigned long long acc[RSZ * CSTRIDE];
    int t = threadIdx.x;
    for (int i = t; i < RSZ * CSTRIDE; i += 1024) acc[i] = 0ULL;
    __syncthreads();
    int p = t & 7, slot = t >> 3;
    int s0 = bstart[blockIdx.x], s1 = bstart[blockIdx.x + 1];
    int j = s0 + slot;
    for (; j + 384 < s1; j += 512) {
        unsigned e0 = spw[j].x, e1 = spw[j + 128].x, e2 = spw[j + 256].x, e3 = spw[j + 384].x;
        unsigned g0 = h2sh[(e0 & LMASK) * 8 + p];
        unsigned g1 = h2sh[(e1 & LMASK) * 8 + p];
        unsigned g2 = h2sh[(e2 & LMASK) * 8 + p];
        unsigned g3 = h2sh[(e3 & LMASK) * 8 + p];
        conv_acc(acc, e0, g0, S16, p);
        conv_acc(acc, e1, g1, S16, p);
        conv_acc(acc, e2, g2, S16, p);
        conv_acc(acc, e3, g3, S16, p);
    }
    for (; j < s1; j += 128) {
        unsigned e = spw[j].x;
        unsigned g = h2sh[(e & LMASK) * 8 + p];
        conv_acc(acc, e, g, S16, p);
    }
    __syncthreads();
    int node0 = blockIdx.x * RSZ;
    for (int i = t; i < RSZ * 8; i += 1024) {
        int ln = i >> 3, pp = i & 7;
        int node = node0 + ln;
        if (node < NN) {
            unsigned long long v = acc[ln * CSTRIDE + pp];
            unsigned kb = (unsigned)cnts[node] * IBIAS;
            float a0 = (float)(int)((unsigned)(v >> 32) - kb) * INV_S16;
            float a1 = (float)(int)((unsigned)(v & 0xFFFFFFFFULL) - kb) * INV_S16;
            float d = dis2[node];
            float2 self = h2s[node * 8 + pp];
            float2 pl = pool2[node * 8 + pp];
            float r0 = pl.x + (a0 + self.x) * d + b2[2 * pp];
            float r1 = pl.y + (a1 + self.y) * d + b2[2 * pp + 1];
            hfin2[node * 8 + pp] = make_float2(fmaxf(r0, 0.f), fmaxf(r1, 0.f));
        }
    }
}

// K9: global max pool per graph (batch = (i*G)//N -> contiguous ranges)
__global__ __launch_bounds__(256) void k_graph_max(
        const float* __restrict__ hfin, float* __restrict__ gbuf) {
    int g = blockIdx.x;
    int start = (g * NN + NG - 1) / NG;
    int end   = ((g + 1) * NN + NG - 1) / NG;
    int f = threadIdx.x & 15, sub = threadIdx.x >> 4;
    float m = -3.402823466e38f;
    for (int i = start + sub; i < end; i += 16)
        m = fmaxf(m, hfin[i * HD + f]);
    __shared__ float lds[256];
    lds[threadIdx.x] = m;
    __syncthreads();
    if (threadIdx.x < 16) {
        float mm = lds[threadIdx.x];
#pragma unroll
        for (int s = 1; s < 16; ++s) mm = fmaxf(mm, lds[s * 16 + threadIdx.x]);
        gbuf[g * HD + threadIdx.x] = mm;
    }
}

// K10: head MLP on [G,16]; one thread per graph row
__global__ __launch_bounds__(256) void k_mlp(
        const float* __restrict__ gbuf,
        const float* __restrict__ Wl1, const float* __restrict__ bl1,
        const float* __restrict__ Wl3, const float* __restrict__ bl3,
        const float* __restrict__ Wl4, const float* __restrict__ bl4,
        float* __restrict__ out) {
    __shared__ float sW1[256], sW3[256], sW4[16], sb1[16], sb3[16];
    __shared__ float sb4;
    int tid = threadIdx.x;
    sW1[tid] = Wl1[tid];
    sW3[tid] = Wl3[tid];
    if (tid < 16) { sW4[tid] = Wl4[tid]; sb1[tid] = bl1[tid]; sb3[tid] = bl3[tid]; }
    if (tid == 0) sb4 = bl4[0];
    __syncthreads();

    float v[16], t1[16], t2[16];
#pragma unroll
    for (int f = 0; f < 16; ++f) v[f] = gbuf[tid * 16 + f];
#pragma unroll
    for (int f = 0; f < 16; ++f) {
        float a = sb1[f] + v[f];
#pragma unroll
        for (int k = 0; k < 16; ++k) a += v[k] * sW1[k * 16 + f];
        t1[f] = rrelu_f(a);
    }
#pragma unroll
    for (int f = 0; f < 16; ++f) {
        float a = sb3[f] + t1[f];
#pragma unroll
        for (int k = 0; k < 16; ++k) a += t1[k] * sW3[k * 16 + f];
        t2[f] = rrelu_f(a);
    }
    float o = sb4;
#pragma unroll
    for (int k = 0; k < 16; ++k) o += t2[k] * sW4[k];
    out[tid] = rrelu_f(o);
}

extern "C" void kernel_launch(void* const* d_in, const int* in_sizes, int n_in,
                              void* d_out, int out_size, void* d_ws, size_t ws_size,
                              hipStream_t stream) {
    const float* x   = (const float*)d_in[0];
    const int*   ei  = (const int*)  d_in[1];   // [2, E] flat
    const float* ew  = (const float*)d_in[3];
    const float* W1  = (const float*)d_in[4];
    const float* b1  = (const float*)d_in[5];
    const float* W2  = (const float*)d_in[6];
    const float* b2  = (const float*)d_in[7];
    const float* Wl1 = (const float*)d_in[8];
    const float* bl1 = (const float*)d_in[9];
    const float* Wl3 = (const float*)d_in[10];
    const float* bl3 = (const float*)d_in[11];
    const float* Wl4 = (const float*)d_in[12];
    const float* bl4 = (const float*)d_in[13];
    const int* row = ei;
    const int* col = ei + NE;

    // workspace layout (floats)
    float* ws = (float*)d_ws;
    float* h1    = ws;                     // NN*HD ; hfin reuses this after conv1
    float* pool  = h1   + NN * HD;         // NN*HD ; hist aliases here pre-k_pool
    float* h2s   = pool + NN * HD;         // NN*HD ; pre aliases here pre-k_pool_h2
    float* dis1  = h2s  + NN * HD;         // NN
    float* dis2  = dis1 + NN;              // NN
    int*   cnts  = (int*)(dis2 + NN);      // NN
    float* gbuf  = (float*)(cnts + NN);    // NG*HD
    unsigned* h1h    = (unsigned*)(gbuf + NG * HD);  // NN*8
    unsigned* h1outh = h1h    + NN * 8;              // NN*8
    unsigned* h2sh   = h1outh + NN * 8;              // NN*8
    uint2*    spw    = (uint2*)(h2sh + NN * 8);      // NE uint2
    int* tot    = (int*)(spw + NE);        // NBUK
    int* bstart = tot + NBUK;              // NBUK+1
    int* hist   = (int*)pool;              // FB*NBUK = 1.6MB (dead before pool written)
    int* pre    = (int*)h2s;               // NBUK*FB = 1.6MB (dead before h2s written)
    float* hfin = h1;

    const int B = 256;

    k_node_prep<<<(NN * HD + B - 1) / B, B, 0, stream>>>(x, W1, h1);
    k_hist     <<<FB, B, 0, stream>>>(col, hist);
    k_scan_a   <<<NBUK, FB, 0, stream>>>(hist, pre, tot);
    k_scan_b   <<<1, 512, 0, stream>>>(tot, bstart);
    k_fill     <<<FB, B, 0, stream>>>(row, col, ew, pre, bstart, spw);
    k_deg      <<<NBUK, 1024, 0, stream>>>(spw, bstart, h1, dis1, dis2, cnts, h1h);
    k_conv1    <<<NBUK, 1024, 0, stream>>>(spw, bstart, h1h, h1, dis1, cnts, b1, h1outh);
    k_pool_h2  <<<NBUK, 1024, 0, stream>>>(spw, bstart, h1outh, W2, dis2,
                                           (float2*)pool, (float2*)h2s, h2sh);
    k_conv2    <<<NBUK, 1024, 0, stream>>>(spw, bstart, h2sh, (const float2*)h2s, dis2,
                                           cnts, (const float2*)pool, b2, (float2*)hfin);
    k_graph_max<<<NG, B, 0, stream>>>(hfin, gbuf);
    k_mlp      <<<1, B, 0, stream>>>(gbuf, Wl1, bl1, Wl3, bl3, Wl4, bl4, (float*)d_out);
}

// Round 7
// 259.499 us; speedup vs baseline: 4.2428x; 1.0267x over previous
//
#include <hip/hip_runtime.h>
#include <hip/hip_fp16.h>
#include <math.h>

#define NN 100000
#define NE 3200000
#define NG 256
#define HD 16
#define FIN 7

// Bucketed counting sort parameters
#define RB 8                 // log2(nodes per bucket)
#define RSZ 256              // nodes per bucket
#define NBUK 391             // ceil(NN / RSZ) ; 391*256 = 100096
#define NBUKP 400            // padded hist/pre_t row stride
#define FB 1024              // fill/hist blocks
#define CHUNK 3125           // NE / FB (exact)
#define SCB 8                // buckets per scan block
#define ASTRIDE 17           // padded u32 LDS accumulator row stride (pool)
#define CSTRIDE 9            // padded u64 LDS accumulator row stride (convs)
#define LMASK 0x1FFFF        // row mask (17 bits)

// fixed-point: 2^16 scale, 2^25 bias per term; exact mod-2^32 decode
#define S16 65536.0f
#define INV_S16 1.52587890625e-5f
#define IBIAS 33554432u      // 2^25
#define S_DEGW 16777216.0f   // 2^24 for edge-weight degree sums (w in [0,1))
#define INV_S_DEGW 5.9604644775390625e-8f

static constexpr float SLOPE = 0.22916666666666666f;  // eval-mode RReLU mean slope

__device__ __forceinline__ float rrelu_f(float a) {
    return a >= 0.f ? a : SLOPE * a;
}

// monotonic float<->uint encoding for atomicMax-based float max
__device__ __forceinline__ unsigned encf(float v) {
    unsigned u = __float_as_uint(v);
    return u ^ (((unsigned)((int)u >> 31)) | 0x80000000u);
}
__device__ __forceinline__ float decf(unsigned u) {
    unsigned m = ((int)u < 0) ? 0x80000000u : 0xFFFFFFFFu;
    return __uint_as_float(u ^ m);
}
#define ENC_NEGINF 0x00800000u

__device__ __forceinline__ float h2f(unsigned short us) {
    __half h = *(__half*)&us;
    return __half2float(h);
}

// ---------------------------------------------------------------------------
// K1: per-block bucket histogram of col>>RB (padded row stride NBUKP)
__global__ __launch_bounds__(256) void k_hist(
        const int* __restrict__ col, int* __restrict__ hist) {
    __shared__ int bins[NBUK];
    for (int i = threadIdx.x; i < NBUK; i += 256) bins[i] = 0;
    __syncthreads();
    int base = blockIdx.x * CHUNK;
    for (int i = threadIdx.x; i < CHUNK; i += 256)
        atomicAdd(&bins[col[base + i] >> RB], 1);
    __syncthreads();
    for (int i = threadIdx.x; i < NBUK; i += 256)
        hist[blockIdx.x * NBUKP + i] = bins[i];
}

// K2a: coalesced per-bucket scan. Block handles SCB buckets: LDS-transpose
// load (rows of hist are coalesced), 64-lane wave scan per bucket, write
// pre_t[block*NBUKP + bucket] so k_fill reads its prefix row coalesced.
__global__ __launch_bounds__(512) void k_scan_a(
        const int* __restrict__ hist, int* __restrict__ pre_t,
        int* __restrict__ tot) {
    __shared__ int s[SCB * (FB + 1)];   // 8 * 1025 * 4 = 32.8 KB
    int t = threadIdx.x;
    int c0 = blockIdx.x * SCB;
    for (int i = t; i < SCB * FB; i += 512) {
        int j = i >> 3, c = i & 7;
        int cc = c0 + c;
        s[c * (FB + 1) + j] = (cc < NBUK) ? hist[j * NBUKP + cc] : 0;
    }
    __syncthreads();
    int w = t >> 6, l = t & 63;         // wave w scans bucket c0+w
    int* sb = &s[w * (FB + 1)];
    int base = l * 16;
    int loc[16];
    int run = 0;
#pragma unroll
    for (int k = 0; k < 16; ++k) { loc[k] = run; run += sb[base + k]; }
    int inc = run;
#pragma unroll
    for (int d = 1; d < 64; d <<= 1) {
        int v = __shfl_up(inc, d, 64);
        if (l >= d) inc += v;
    }
    int excl = inc - run;
    int cc = c0 + w;
    if (cc < NBUK) {
#pragma unroll
        for (int k = 0; k < 16; ++k) sb[base + k] = excl + loc[k];
        if (l == 63) tot[cc] = inc;
    }
    __syncthreads();
    for (int i = t; i < SCB * FB; i += 512) {
        int j = i >> 3, c = i & 7;
        int cc2 = c0 + c;
        if (cc2 < NBUK) pre_t[j * NBUKP + cc2] = s[c * (FB + 1) + j];
    }
}

// K2b: scan bucket totals -> bstart[0..NBUK]
__global__ __launch_bounds__(512) void k_scan_b(
        const int* __restrict__ tot, int* __restrict__ bstart) {
    __shared__ int s[512];
    int t = threadIdx.x;
    int v = (t < NBUK) ? tot[t] : 0;
    s[t] = v;
    __syncthreads();
    for (int d = 1; d < 512; d <<= 1) {
        int add = (t >= d) ? s[t - d] : 0;
        __syncthreads();
        s[t] += add;
        __syncthreads();
    }
    if (t < NBUK) bstart[t + 1] = s[t];
    if (t == 0) bstart[0] = 0;
}

// K3: fill (SoA: sp u32 + swh fp16) with LDS staging into bucket order.
__global__ __launch_bounds__(256) void k_fill(
        const int* __restrict__ row, const int* __restrict__ col,
        const float* __restrict__ ew,
        const int* __restrict__ pre_t, const int* __restrict__ bstart,
        unsigned* __restrict__ sp, unsigned short* __restrict__ swh) {
    __shared__ int lcnt[NBUK];
    __shared__ int gofs[NBUK];
    __shared__ int part[256];
    __shared__ unsigned ssp[CHUNK];
    __shared__ unsigned short ssw[CHUNK];
    __shared__ unsigned short sbuk[CHUNK];
    int t = threadIdx.x;
    for (int i = t; i < NBUK; i += 256) {
        lcnt[i] = 0;
        gofs[i] = bstart[i] + pre_t[blockIdx.x * NBUKP + i];   // lbase for now
    }
    __syncthreads();
    int base = blockIdx.x * CHUNK;
    for (int i = t; i < CHUNK; i += 256)
        atomicAdd(&lcnt[col[base + i] >> RB], 1);
    __syncthreads();
    // exclusive scan of lcnt[0..NBUK): 2 buckets/thread + block scan over 256
    int k0 = t * 2;
    int c0 = (k0 + 0 < NBUK) ? lcnt[k0 + 0] : 0;
    int c1 = (k0 + 1 < NBUK) ? lcnt[k0 + 1] : 0;
    int gsum = c0 + c1;
    part[t] = gsum;
    __syncthreads();
    for (int d = 1; d < 256; d <<= 1) {
        int add = (t >= d) ? part[t - d] : 0;
        __syncthreads();
        part[t] += add;
        __syncthreads();
    }
    {
        int run = part[t] - gsum;
        int e0 = run, e1 = run + c0;
        if (k0 + 0 < NBUK) { gofs[k0 + 0] -= e0; lcnt[k0 + 0] = e0; }
        if (k0 + 1 < NBUK) { gofs[k0 + 1] -= e1; lcnt[k0 + 1] = e1; }
    }
    __syncthreads();
    for (int i = t; i < CHUNK; i += 256) {
        int c = col[base + i];
        int b = c >> RB;
        int s = atomicAdd(&lcnt[b], 1);
        ssp[s] = ((unsigned)(c & (RSZ - 1)) << 17) | (unsigned)row[base + i];
        __half hv = __float2half_rn(ew[base + i]);
        ssw[s] = *(unsigned short*)&hv;
        sbuk[s] = (unsigned short)b;
    }
    __syncthreads();
    for (int s = t; s < CHUNK; s += 256) {
        int g = s + gofs[sbuk[s]];
        sp[g] = ssp[s];
        swh[g] = ssw[s];
    }
}

// K4: degrees (packed u64 atomic/edge) + FUSED node_prep: h1 = x@W1 computed
// in-bucket; writes h1 (fp32, for conv1 self term) and h1h = half2(h1*dis1).
__global__ __launch_bounds__(1024) void k_deg(
        const unsigned* __restrict__ sp, const unsigned short* __restrict__ swh,
        const int* __restrict__ bstart,
        const float* __restrict__ x, const float* __restrict__ W1,
        float* __restrict__ h1, float* __restrict__ dis1,
        float* __restrict__ dis2, int* __restrict__ cnts,
        unsigned* __restrict__ h1h) {
    __shared__ unsigned long long sdeg[RSZ];
    __shared__ float sdis[RSZ];
    __shared__ float sW1[FIN * HD];
    int t = threadIdx.x;
    if (t < FIN * HD) sW1[t] = W1[t];
    if (t < RSZ) sdeg[t] = 0ULL;
    __syncthreads();
    int s0 = bstart[blockIdx.x], s1 = bstart[blockIdx.x + 1];
    int j = s0 + t;
    for (; j + 3072 < s1; j += 4096) {
        unsigned e0 = sp[j], e1 = sp[j + 1024], e2 = sp[j + 2048], e3 = sp[j + 3072];
        float w0 = h2f(swh[j]), w1 = h2f(swh[j + 1024]);
        float w2 = h2f(swh[j + 2048]), w3 = h2f(swh[j + 3072]);
        atomicAdd(&sdeg[e0 >> 17], (1ULL << 32) |
                  (unsigned long long)(unsigned)__float2int_rn(w0 * S_DEGW));
        atomicAdd(&sdeg[e1 >> 17], (1ULL << 32) |
                  (unsigned long long)(unsigned)__float2int_rn(w1 * S_DEGW));
        atomicAdd(&sdeg[e2 >> 17], (1ULL << 32) |
                  (unsigned long long)(unsigned)__float2int_rn(w2 * S_DEGW));
        atomicAdd(&sdeg[e3 >> 17], (1ULL << 32) |
                  (unsigned long long)(unsigned)__float2int_rn(w3 * S_DEGW));
    }
    for (; j < s1; j += 1024) {
        unsigned e = sp[j];
        float w = h2f(swh[j]);
        atomicAdd(&sdeg[e >> 17], (1ULL << 32) |
                  (unsigned long long)(unsigned)__float2int_rn(w * S_DEGW));
    }
    __syncthreads();
    int node0 = blockIdx.x * RSZ;
    if (t < RSZ && node0 + t < NN) {
        unsigned long long v = sdeg[t];
        unsigned cnt = (unsigned)(v >> 32);
        float wsum = (float)(unsigned)(v & 0xFFFFFFFFULL) * INV_S_DEGW;
        float d1 = rsqrtf(wsum + 1.f);
        dis1[node0 + t] = d1;
        sdis[t] = d1;
        dis2[node0 + t] = rsqrtf((float)cnt + 1.f);
        cnts[node0 + t] = (int)cnt;
    }
    __syncthreads();
    for (int i = t; i < RSZ * 8; i += 1024) {
        int ln = i >> 3, p = i & 7;
        int node = node0 + ln;
        if (node < NN) {
            float a0 = 0.f, a1 = 0.f;
#pragma unroll
            for (int k = 0; k < FIN; ++k) {
                float xv = x[node * FIN + k];
                a0 += xv * sW1[k * HD + 2 * p];
                a1 += xv * sW1[k * HD + 2 * p + 1];
            }
            h1[node * HD + 2 * p] = a0;
            h1[node * HD + 2 * p + 1] = a1;
            float d = sdis[ln];
            __half2 hh = __floats2half2_rn(a0 * d, a1 * d);
            h1h[node * 8 + p] = *(unsigned*)&hh;
        }
    }
}

// packed u64 fixed-point accumulate of one uint2 gather (4 features)
__device__ __forceinline__ void conv_acc2(unsigned long long* acc, unsigned ex,
                                          uint2 g, float w, int p2) {
    float2 fa = __half22float2(*(__half2*)&g.x);
    float2 fb = __half22float2(*(__half2*)&g.y);
    unsigned qa0 = (unsigned)__float2int_rn(fa.x * w) + IBIAS;
    unsigned qa1 = (unsigned)__float2int_rn(fa.y * w) + IBIAS;
    unsigned qb0 = (unsigned)__float2int_rn(fb.x * w) + IBIAS;
    unsigned qb1 = (unsigned)__float2int_rn(fb.y * w) + IBIAS;
    int lc = ex >> 17;
    atomicAdd(&acc[lc * CSTRIDE + 2 * p2],
              ((unsigned long long)qa0 << 32) | (unsigned long long)qa1);
    atomicAdd(&acc[lc * CSTRIDE + 2 * p2 + 1],
              ((unsigned long long)qb0 << 32) | (unsigned long long)qb1);
}

// K5: conv1 aggregate; 4 lanes/edge, 8B gathers
__global__ __launch_bounds__(1024) void k_conv1(
        const unsigned* __restrict__ sp, const unsigned short* __restrict__ swh,
        const int* __restrict__ bstart,
        const unsigned* __restrict__ h1h, const float* __restrict__ h1,
        const float* __restrict__ dis1, const int* __restrict__ cnts,
        const float* __restrict__ b1, unsigned* __restrict__ h1outh) {
    __shared__ unsigned long long acc[RSZ * CSTRIDE];
    int t = threadIdx.x;
    for (int i = t; i < RSZ * CSTRIDE; i += 1024) acc[i] = 0ULL;
    __syncthreads();
    int p2 = t & 3, slot = t >> 2;   // 256 slots x 4 feature-quads
    const uint2* h1h2 = (const uint2*)h1h;
    int s0 = bstart[blockIdx.x], s1 = bstart[blockIdx.x + 1];
    int j = s0 + slot;
    for (; j + 768 < s1; j += 1024) {
        unsigned e0 = sp[j], e1 = sp[j + 256], e2 = sp[j + 512], e3 = sp[j + 768];
        float w0 = h2f(swh[j]) * S16, w1 = h2f(swh[j + 256]) * S16;
        float w2 = h2f(swh[j + 512]) * S16, w3 = h2f(swh[j + 768]) * S16;
        uint2 g0 = h1h2[(e0 & LMASK) * 4 + p2];
        uint2 g1 = h1h2[(e1 & LMASK) * 4 + p2];
        uint2 g2 = h1h2[(e2 & LMASK) * 4 + p2];
        uint2 g3 = h1h2[(e3 & LMASK) * 4 + p2];
        conv_acc2(acc, e0, g0, w0, p2);
        conv_acc2(acc, e1, g1, w1, p2);
        conv_acc2(acc, e2, g2, w2, p2);
        conv_acc2(acc, e3, g3, w3, p2);
    }
    for (; j < s1; j += 256) {
        unsigned e = sp[j];
        float w = h2f(swh[j]) * S16;
        uint2 g = h1h2[(e & LMASK) * 4 + p2];
        conv_acc2(acc, e, g, w, p2);
    }
    __syncthreads();
    int node0 = blockIdx.x * RSZ;
    for (int i = t; i < RSZ * 8; i += 1024) {
        int ln = i >> 3, pp = i & 7;
        int node = node0 + ln;
        if (node < NN) {
            unsigned long long v = acc[ln * CSTRIDE + pp];
            unsigned kb = (unsigned)cnts[node] * IBIAS;   // mod-2^32 exact decode
            float a0 = (float)(int)((unsigned)(v >> 32) - kb) * INV_S16;
            float a1 = (float)(int)((unsigned)(v & 0xFFFFFFFFULL) - kb) * INV_S16;
            float d = dis1[node];
            float r0 = a0 * d + h1[node * HD + 2 * pp] * d * d + b1[2 * pp];
            float r1 = a1 * d + h1[node * HD + 2 * pp + 1] * d * d + b1[2 * pp + 1];
            __half2 hh = __floats2half2_rn(r0, r1);
            h1outh[node * 8 + pp] = *(unsigned*)&hh;
        }
    }
}

// K6: neighbor max pool (4 lanes/edge, 8B gathers) + FUSED h2 = (pool@W2)*dis2
__global__ __launch_bounds__(1024) void k_pool_h2(
        const unsigned* __restrict__ sp, const int* __restrict__ bstart,
        const unsigned* __restrict__ h1outh, const float* __restrict__ W2,
        const float* __restrict__ dis2,
        float2* __restrict__ pool2, float2* __restrict__ h2s,
        unsigned* __restrict__ h2sh) {
    __shared__ unsigned acc[RSZ * ASTRIDE];
    __shared__ float sW2[256];
    int t = threadIdx.x;
    if (t < 256) sW2[t] = W2[t];
    for (int i = t; i < RSZ * ASTRIDE; i += 1024) acc[i] = ENC_NEGINF;
    __syncthreads();
    int p2 = t & 3, slot = t >> 2;
    const uint2* hv2 = (const uint2*)h1outh;
    int s0 = bstart[blockIdx.x], s1 = bstart[blockIdx.x + 1];
    int j = s0 + slot;
    for (; j + 768 < s1; j += 1024) {
        unsigned e0 = sp[j], e1 = sp[j + 256], e2 = sp[j + 512], e3 = sp[j + 768];
        uint2 g0 = hv2[(e0 & LMASK) * 4 + p2];
        uint2 g1 = hv2[(e1 & LMASK) * 4 + p2];
        uint2 g2 = hv2[(e2 & LMASK) * 4 + p2];
        uint2 g3 = hv2[(e3 & LMASK) * 4 + p2];
        float2 f;
        unsigned* a;
        a = &acc[(e0 >> 17) * ASTRIDE + 4 * p2];
        f = __half22float2(*(__half2*)&g0.x);
        atomicMax(a + 0, encf(f.x)); atomicMax(a + 1, encf(f.y));
        f = __half22float2(*(__half2*)&g0.y);
        atomicMax(a + 2, encf(f.x)); atomicMax(a + 3, encf(f.y));
        a = &acc[(e1 >> 17) * ASTRIDE + 4 * p2];
        f = __half22float2(*(__half2*)&g1.x);
        atomicMax(a + 0, encf(f.x)); atomicMax(a + 1, encf(f.y));
        f = __half22float2(*(__half2*)&g1.y);
        atomicMax(a + 2, encf(f.x)); atomicMax(a + 3, encf(f.y));
        a = &acc[(e2 >> 17) * ASTRIDE + 4 * p2];
        f = __half22float2(*(__half2*)&g2.x);
        atomicMax(a + 0, encf(f.x)); atomicMax(a + 1, encf(f.y));
        f = __half22float2(*(__half2*)&g2.y);
        atomicMax(a + 2, encf(f.x)); atomicMax(a + 3, encf(f.y));
        a = &acc[(e3 >> 17) * ASTRIDE + 4 * p2];
        f = __half22float2(*(__half2*)&g3.x);
        atomicMax(a + 0, encf(f.x)); atomicMax(a + 1, encf(f.y));
        f = __half22float2(*(__half2*)&g3.y);
        atomicMax(a + 2, encf(f.x)); atomicMax(a + 3, encf(f.y));
    }
    for (; j < s1; j += 256) {
        unsigned e = sp[j];
        uint2 g = hv2[(e & LMASK) * 4 + p2];
        unsigned* a = &acc[(e >> 17) * ASTRIDE + 4 * p2];
        float2 f = __half22float2(*(__half2*)&g.x);
        atomicMax(a + 0, encf(f.x)); atomicMax(a + 1, encf(f.y));
        f = __half22float2(*(__half2*)&g.y);
        atomicMax(a + 2, encf(f.x)); atomicMax(a + 3, encf(f.y));
    }
    __syncthreads();
    int node0 = blockIdx.x * RSZ;
    // epilogue 1: pool = max(agg, self); write pool2; stash pool floats in acc
    for (int i = t; i < RSZ * 8; i += 1024) {
        int ln = i >> 3, pp = i & 7;
        int node = node0 + ln;
        if (node < NN) {
            unsigned sh = h1outh[node * 8 + pp];
            float2 sf = __half22float2(*(__half2*)&sh);
            float m0 = fmaxf(decf(acc[ln * ASTRIDE + 2 * pp]),     sf.x);
            float m1 = fmaxf(decf(acc[ln * ASTRIDE + 2 * pp + 1]), sf.y);
            pool2[node * 8 + pp] = make_float2(m0, m1);
            acc[ln * ASTRIDE + 2 * pp]     = __float_as_uint(m0);
            acc[ln * ASTRIDE + 2 * pp + 1] = __float_as_uint(m1);
        }
    }
    __syncthreads();
    // epilogue 2 (fused k_h2): h2s = (pool @ W2) * dis2, fp32 + fp16 copies
    for (int i = t; i < RSZ * 8; i += 1024) {
        int ln = i >> 3, pp = i & 7;
        int node = node0 + ln;
        if (node < NN) {
            float a0 = 0.f, a1 = 0.f;
#pragma unroll
            for (int k = 0; k < HD; ++k) {
                float pv = __uint_as_float(acc[ln * ASTRIDE + k]);
                a0 += pv * sW2[k * HD + 2 * pp];
                a1 += pv * sW2[k * HD + 2 * pp + 1];
            }
            float d = dis2[node];
            a0 *= d; a1 *= d;
            h2s[node * 8 + pp] = make_float2(a0, a1);
            __half2 hh = __floats2half2_rn(a0, a1);
            h2sh[node * 8 + pp] = *(unsigned*)&hh;
        }
    }
}

// K8: conv2 aggregate (4 lanes/edge) + fused residual-relu epilogue -> hfin
__global__ __launch_bounds__(1024) void k_conv2(
        const unsigned* __restrict__ sp, const int* __restrict__ bstart,
        const unsigned* __restrict__ h2sh, const float2* __restrict__ h2s,
        const float* __restrict__ dis2, const int* __restrict__ cnts,
        const float2* __restrict__ pool2, const float* __restrict__ b2,
        float2* __restrict__ hfin2) {
    __shared__ unsigned long long acc[RSZ * CSTRIDE];
    int t = threadIdx.x;
    for (int i = t; i < RSZ * CSTRIDE; i += 1024) acc[i] = 0ULL;
    __syncthreads();
    int p2 = t & 3, slot = t >> 2;
    const uint2* hv2 = (const uint2*)h2sh;
    int s0 = bstart[blockIdx.x], s1 = bstart[blockIdx.x + 1];
    int j = s0 + slot;
    for (; j + 768 < s1; j += 1024) {
        unsigned e0 = sp[j], e1 = sp[j + 256], e2 = sp[j + 512], e3 = sp[j + 768];
        uint2 g0 = hv2[(e0 & LMASK) * 4 + p2];
        uint2 g1 = hv2[(e1 & LMASK) * 4 + p2];
        uint2 g2 = hv2[(e2 & LMASK) * 4 + p2];
        uint2 g3 = hv2[(e3 & LMASK) * 4 + p2];
        conv_acc2(acc, e0, g0, S16, p2);
        conv_acc2(acc, e1, g1, S16, p2);
        conv_acc2(acc, e2, g2, S16, p2);
        conv_acc2(acc, e3, g3, S16, p2);
    }
    for (; j < s1; j += 256) {
        unsigned e = sp[j];
        uint2 g = hv2[(e & LMASK) * 4 + p2];
        conv_acc2(acc, e, g, S16, p2);
    }
    __syncthreads();
    int node0 = blockIdx.x * RSZ;
    for (int i = t; i < RSZ * 8; i += 1024) {
        int ln = i >> 3, pp = i & 7;
        int node = node0 + ln;
        if (node < NN) {
            unsigned long long v = acc[ln * CSTRIDE + pp];
            unsigned kb = (unsigned)cnts[node] * IBIAS;
            float a0 = (float)(int)((unsigned)(v >> 32) - kb) * INV_S16;
            float a1 = (float)(int)((unsigned)(v & 0xFFFFFFFFULL) - kb) * INV_S16;
            float d = dis2[node];
            float2 self = h2s[node * 8 + pp];
            float2 pl = pool2[node * 8 + pp];
            float r0 = pl.x + (a0 + self.x) * d + b2[2 * pp];
            float r1 = pl.y + (a1 + self.y) * d + b2[2 * pp + 1];
            hfin2[node * 8 + pp] = make_float2(fmaxf(r0, 0.f), fmaxf(r1, 0.f));
        }
    }
}

// K9: global max pool per graph (batch = (i*G)//N -> contiguous ranges)
__global__ __launch_bounds__(256) void k_graph_max(
        const float* __restrict__ hfin, float* __restrict__ gbuf) {
    int g = blockIdx.x;
    int start = (g * NN + NG - 1) / NG;
    int end   = ((g + 1) * NN + NG - 1) / NG;
    int f = threadIdx.x & 15, sub = threadIdx.x >> 4;
    float m = -3.402823466e38f;
    for (int i = start + sub; i < end; i += 16)
        m = fmaxf(m, hfin[i * HD + f]);
    __shared__ float lds[256];
    lds[threadIdx.x] = m;
    __syncthreads();
    if (threadIdx.x < 16) {
        float mm = lds[threadIdx.x];
#pragma unroll
        for (int s = 1; s < 16; ++s) mm = fmaxf(mm, lds[s * 16 + threadIdx.x]);
        gbuf[g * HD + threadIdx.x] = mm;
    }
}

// K10: head MLP on [G,16]; one thread per graph row
__global__ __launch_bounds__(256) void k_mlp(
        const float* __restrict__ gbuf,
        const float* __restrict__ Wl1, const float* __restrict__ bl1,
        const float* __restrict__ Wl3, const float* __restrict__ bl3,
        const float* __restrict__ Wl4, const float* __restrict__ bl4,
        float* __restrict__ out) {
    __shared__ float sW1[256], sW3[256], sW4[16], sb1[16], sb3[16];
    __shared__ float sb4;
    int tid = threadIdx.x;
    sW1[tid] = Wl1[tid];
    sW3[tid] = Wl3[tid];
    if (tid < 16) { sW4[tid] = Wl4[tid]; sb1[tid] = bl1[tid]; sb3[tid] = bl3[tid]; }
    if (tid == 0) sb4 = bl4[0];
    __syncthreads();

    float v[16], t1[16], t2[16];
#pragma unroll
    for (int f = 0; f < 16; ++f) v[f] = gbuf[tid * 16 + f];
#pragma unroll
    for (int f = 0; f < 16; ++f) {
        float a = sb1[f] + v[f];
#pragma unroll
        for (int k = 0; k < 16; ++k) a += v[k] * sW1[k * 16 + f];
        t1[f] = rrelu_f(a);
    }
#pragma unroll
    for (int f = 0; f < 16; ++f) {
        float a = sb3[f] + t1[f];
#pragma unroll
        for (int k = 0; k < 16; ++k) a += t1[k] * sW3[k * 16 + f];
        t2[f] = rrelu_f(a);
    }
    float o = sb4;
#pragma unroll
    for (int k = 0; k < 16; ++k) o += t2[k] * sW4[k];
    out[tid] = rrelu_f(o);
}

extern "C" void kernel_launch(void* const* d_in, const int* in_sizes, int n_in,
                              void* d_out, int out_size, void* d_ws, size_t ws_size,
                              hipStream_t stream) {
    const float* x   = (const float*)d_in[0];
    const int*   ei  = (const int*)  d_in[1];   // [2, E] flat
    const float* ew  = (const float*)d_in[3];
    const float* W1  = (const float*)d_in[4];
    const float* b1  = (const float*)d_in[5];
    const float* W2  = (const float*)d_in[6];
    const float* b2  = (const float*)d_in[7];
    const float* Wl1 = (const float*)d_in[8];
    const float* bl1 = (const float*)d_in[9];
    const float* Wl3 = (const float*)d_in[10];
    const float* bl3 = (const float*)d_in[11];
    const float* Wl4 = (const float*)d_in[12];
    const float* bl4 = (const float*)d_in[13];
    const int* row = ei;
    const int* col = ei + NE;

    // workspace layout (floats)
    float* ws = (float*)d_ws;
    float* h1    = ws;                     // NN*HD ; hfin reuses this after conv1
    float* pool  = h1   + NN * HD;         // NN*HD ; hist aliases here (dead before pool)
    float* h2s   = pool + NN * HD;         // NN*HD ; pre_t aliases here (dead before h2s)
    float* dis1  = h2s  + NN * HD;         // NN
    float* dis2  = dis1 + NN;              // NN
    int*   cnts  = (int*)(dis2 + NN);      // NN
    float* gbuf  = (float*)(cnts + NN);    // NG*HD
    unsigned* h1h    = (unsigned*)(gbuf + NG * HD);  // NN*8
    unsigned* h1outh = h1h    + NN * 8;              // NN*8
    unsigned* h2sh   = h1outh + NN * 8;              // NN*8
    unsigned* sp     = h2sh   + NN * 8;              // NE u32
    unsigned short* swh = (unsigned short*)(sp + NE);  // NE u16
    int* tot    = (int*)(swh + NE + (NE & 1));       // NBUK (4B aligned)
    int* bstart = tot + NBUK;              // NBUK+1
    int* hist   = (int*)pool;              // FB*NBUKP = 1.64MB (dead before pool)
    int* pre_t  = (int*)h2s;               // FB*NBUKP = 1.64MB (dead before h2s)
    float* hfin = h1;

    const int B = 256;

    k_hist     <<<FB, B, 0, stream>>>(col, hist);
    k_scan_a   <<<(NBUK + SCB - 1) / SCB, 512, 0, stream>>>(hist, pre_t, tot);
    k_scan_b   <<<1, 512, 0, stream>>>(tot, bstart);
    k_fill     <<<FB, B, 0, stream>>>(row, col, ew, pre_t, bstart, sp, swh);
    k_deg      <<<NBUK, 1024, 0, stream>>>(sp, swh, bstart, x, W1, h1,
                                           dis1, dis2, cnts, h1h);
    k_conv1    <<<NBUK, 1024, 0, stream>>>(sp, swh, bstart, h1h, h1, dis1,
                                           cnts, b1, h1outh);
    k_pool_h2  <<<NBUK, 1024, 0, stream>>>(sp, bstart, h1outh, W2, dis2,
                                           (float2*)pool, (float2*)h2s, h2sh);
    k_conv2    <<<NBUK, 1024, 0, stream>>>(sp, bstart, h2sh, (const float2*)h2s, dis2,
                                           cnts, (const float2*)pool, b2, (float2*)hfin);
    k_graph_max<<<NG, B, 0, stream>>>(hfin, gbuf);
    k_mlp      <<<1, B, 0, stream>>>(gbuf, Wl1, bl1, Wl3, bl3, Wl4, bl4, (float*)d_out);
}